// Round 14
// baseline (329.883 us; speedup 1.0000x reference)
//
#include <hip/hip_runtime.h>
#include <math.h>

#define EPSF 1e-7f

typedef unsigned short ushort_t;
typedef __attribute__((ext_vector_type(8))) short bf16x8;
typedef __attribute__((ext_vector_type(4))) float f32x4;

// fast hardware transcendentals (v_exp_f32 / v_log_f32), ~2-4 ulp
__device__ __forceinline__ float fsinh(float x) { return 0.5f * (__expf(x) - __expf(-x)); }
__device__ __forceinline__ float arcosh_f(float x) {
    x = fmaxf(x, 1.0f + EPSF);
    return __logf(x + sqrtf(x * x - 1.0f));
}

__device__ __forceinline__ unsigned short f2bf(float f) {
    union { float f; unsigned u; } c; c.f = f;
    unsigned r = c.u + 0x7FFFu + ((c.u >> 16) & 1u);
    return (unsigned short)(r >> 16);
}
__device__ __forceinline__ float bf2f(unsigned short u) {
    union { unsigned u; float f; } c; c.u = ((unsigned)u) << 16;
    return c.f;
}

__device__ __forceinline__ float wredsum(float v) {
#pragma unroll
    for (int off = 32; off; off >>= 1) v += __shfl_xor(v, off, 64);
    return v;
}

__device__ __forceinline__ void llds16(const void* g, void* l) {
    __builtin_amdgcn_global_load_lds((const __attribute__((address_space(1))) unsigned int*)g,
                                     (__attribute__((address_space(3))) unsigned int*)l,
                                     16, 0, 0);
}

// ---------- K1: xt0 = log_map_zero(x) -> bf16, upper half of Abuf rows ----------
__global__ __launch_bounds__(64) void k_log0(const float* __restrict__ x,
                                             char* __restrict__ Abase, int N) {
    int i = blockIdx.x, t = threadIdx.x;
    float2 v = *reinterpret_cast<const float2*>(x + (size_t)i * 128 + 2 * t);
    float y0 = __shfl(v.x, 0, 64);
    float a0 = (t == 0) ? 0.f : v.x;
    float s = wredsum(a0 * a0 + v.y * v.y);
    float dist = arcosh_f(y0 + EPSF);
    float scl = dist / sqrtf(s + EPSF);
    ushort2 o;
    o.x = f2bf(scl * a0);
    o.y = f2bf(scl * v.y);
    *reinterpret_cast<ushort2*>(Abase + (size_t)i * 512 + 256 + 4 * t) = o;
}

// ---------- bucket partition: 1024-node buckets ----------
__global__ __launch_bounds__(256) void k_c1(const int* __restrict__ edst,
                                            int* __restrict__ gcnt,
                                            int E, int NBKT, int EPB) {
    __shared__ int cnt[64];
    int blk = blockIdx.x, t = threadIdx.x;
    for (int i = t; i < NBKT; i += 256) cnt[i] = 0;
    __syncthreads();
    int lo = blk * EPB, hi = min(lo + EPB, E);
    for (int e = lo + t; e < hi; e += 256) atomicAdd(&cnt[edst[e] >> 10], 1);
    __syncthreads();
    for (int i = t; i < NBKT; i += 256) gcnt[blk * NBKT + i] = cnt[i];
}

__global__ __launch_bounds__(64) void k_c2(int* __restrict__ gcnt,
                                           int* __restrict__ bstart, int NBLK, int NBKT) {
    __shared__ int sh[10816];
    __shared__ int tot[64];
    __shared__ int bs[65];
    int t = threadIdx.x;
    int total = NBLK * NBKT;
    for (int i = t; i < total; i += 64) sh[i] = gcnt[i];
    __syncthreads();
    if (t < NBKT) {
        int run = 0;
        for (int blk = 0; blk < NBLK; ++blk) {
            int idx = blk * NBKT + t;
            int c = sh[idx]; sh[idx] = run; run += c;
        }
        tot[t] = run;
    }
    __syncthreads();
    if (t == 0) {
        int r = 0;
        for (int b = 0; b < NBKT; ++b) { bs[b] = r; r += tot[b]; }
        bs[NBKT] = r;
    }
    __syncthreads();
    if (t < NBKT) {
        bstart[t] = bs[t];
        if (t == 0) bstart[NBKT] = bs[NBKT];
    }
    for (int i = t; i < total; i += 64) gcnt[i] = sh[i] + bs[i % NBKT];
}

// c3: place packed (dlo<<17 | src) into bucket regions (src < 2^17 since N = 50k)
__global__ __launch_bounds__(256) void k_c3(const int* __restrict__ esrc,
                                            const int* __restrict__ edst,
                                            const int* __restrict__ gcnt,
                                            int* __restrict__ ebuf,
                                            int E, int NBKT, int EPB) {
    __shared__ int cur[64];
    int blk = blockIdx.x, t = threadIdx.x;
    for (int i = t; i < NBKT; i += 256) cur[i] = 0;
    __syncthreads();
    int lo = blk * EPB, hi = min(lo + EPB, E);
    for (int e = lo + t; e < hi; e += 256) {
        int d = edst[e], s = esrc[e];
        int b = d >> 10;
        int r = atomicAdd(&cur[b], 1);
        ebuf[gcnt[blk * NBKT + b] + r] = ((d & 1023) << 17) | s;
    }
}

// ---------- c4: per-bucket exact CSR (L2-resident scatter), packed ebuf ----------
__global__ __launch_bounds__(256) void k_c4(const int* __restrict__ ebuf,
                                            const int* __restrict__ bstart,
                                            int* __restrict__ row_ptr,
                                            int* __restrict__ srcl,
                                            int N, int NBKT, int E) {
    __shared__ int cnt[1024];
    __shared__ int cur[1024];
    __shared__ int sb[256];
    int b = blockIdx.x, t = threadIdx.x;
    int lo = b << 10;
    int nn = min(1024, N - lo);
    for (int i = t; i < 1024; i += 256) cnt[i] = 0;
    __syncthreads();
    int es = bstart[b], ee = bstart[b + 1];
    for (int e = es + t; e < ee; e += 256) atomicAdd(&cnt[ebuf[e] >> 17], 1);
    __syncthreads();
    int base = t * 4;
    int c0 = cnt[base], c1 = cnt[base + 1], c2 = cnt[base + 2], c3 = cnt[base + 3];
    int ts = c0 + c1 + c2 + c3;
    sb[t] = ts; __syncthreads();
    for (int st = 1; st < 256; st <<= 1) {
        int v = (t >= st) ? sb[t - st] : 0;
        __syncthreads();
        sb[t] += v;
        __syncthreads();
    }
    int run = es + sb[t] - ts;
    int rp[4];
    rp[0] = run; rp[1] = run + c0; rp[2] = rp[1] + c1; rp[3] = rp[2] + c2;
#pragma unroll
    for (int q = 0; q < 4; ++q) {
        cur[base + q] = rp[q];
        if (base + q < nn) row_ptr[lo + base + q] = rp[q];
    }
    if (b == NBKT - 1 && t == 0) row_ptr[N] = E;
    __syncthreads();
    for (int e = es + t; e < ee; e += 256) {
        int p = ebuf[e];
        int r = atomicAdd(&cur[p >> 17], 1);
        srcl[r] = p & 0x1FFFF;
    }
}

// ---------- K3: agg (8-way unrolled gather) + radial-collapsed epilogue ----------
__global__ __launch_bounds__(64) void k_agg(const char* __restrict__ Abase,
                                            const int* __restrict__ row_ptr,
                                            const int* __restrict__ srcl,
                                            ushort_t* __restrict__ Ab, int N) {
    int i = blockIdx.x, t = threadIdx.x;
    const char* base = Abase + 256 + 4 * t;
    ushort2 sv = *reinterpret_cast<const ushort2*>(base + (size_t)i * 512);
    float p0[8], p1[8];
    p0[0] = bf2f(sv.x); p1[0] = bf2f(sv.y);
#pragma unroll
    for (int q = 1; q < 8; ++q) { p0[q] = 0.f; p1[q] = 0.f; }
    int b = row_ptr[i], e = row_ptr[i + 1];
    int k = b;
    for (; k + 8 <= e; k += 8) {
        int s[8];
#pragma unroll
        for (int q = 0; q < 8; ++q) s[q] = srcl[k + q];
        ushort2 v[8];
#pragma unroll
        for (int q = 0; q < 8; ++q)
            v[q] = *reinterpret_cast<const ushort2*>(base + (size_t)s[q] * 512);
#pragma unroll
        for (int q = 0; q < 8; ++q) { p0[q] += bf2f(v[q].x); p1[q] += bf2f(v[q].y); }
    }
    for (; k < e; ++k) {
        int s = srcl[k];
        ushort2 v = *reinterpret_cast<const ushort2*>(base + (size_t)s * 512);
        p0[0] += bf2f(v.x); p1[0] += bf2f(v.y);
    }
    float u0 = ((p0[0] + p0[1]) + (p0[2] + p0[3])) + ((p0[4] + p0[5]) + (p0[6] + p0[7]));
    float u1 = ((p1[0] + p1[1]) + (p1[2] + p1[3])) + ((p1[4] + p1[5]) + (p1[6] + p1[7]));
    if (t == 0) u0 = 0.f;
    float s1 = wredsum(u0 * u0 + u1 * u1);
    float n = sqrtf(fmaxf(s1 + EPSF, 1e-6f));
    float fac = fsinh(fminf(n, 50.f)) / n;
    float S2 = fac * fac * s1;
    float first = sqrtf(1.f + S2);
    float dist = arcosh_f(first + EPSF);
    float C = dist / sqrtf(S2 + EPSF) * fac;
    ushort2 o;
    o.x = f2bf(C * u0);
    o.y = f2bf(C * u1);
    *reinterpret_cast<ushort2*>(Ab + (size_t)i * 256 + 2 * t) = o;
}

// ---------- W conversion (all 3 layers, one launch) ----------
__global__ void k_convw3(const float* __restrict__ W0, const float* __restrict__ W1,
                         const float* __restrict__ W2,
                         ushort_t* __restrict__ Wb0, ushort_t* __restrict__ Wb1,
                         ushort_t* __restrict__ Wb2,
                         int o1, int i1, int Kp1, int o2, int i2, int Kp2,
                         int o3, int i3, int Kp3, int t1, int t2, int t3) {
    int idx = blockIdx.x * blockDim.x + threadIdx.x;
    const float* W; ushort_t* Wb; int ncols, K, Kp, shift;
    if (idx < t1) { W = W0; Wb = Wb0; ncols = o1; K = i1; Kp = Kp1; shift = 1; }
    else if (idx < t1 + t2) { idx -= t1; W = W1; Wb = Wb1; ncols = o2; K = i2; Kp = Kp2; shift = 0; }
    else if (idx < t1 + t2 + t3) { idx -= t1 + t2; W = W2; Wb = Wb2; ncols = o3; K = i3; Kp = Kp3; shift = 0; }
    else return;
    int o = idx / Kp, kk = idx - o * Kp;
    int ks = kk - shift;
    float v = 0.f;
    if (o < ncols && ks >= 0 && ks < K) v = W[(size_t)o * K + ks];
    Wb[idx] = f2bf(v);
}

// ---------- MFMA bf16 GEMM: Yb[M x ncols] = A @ W^T + bias, bf16 output ----------
__global__ __launch_bounds__(256) void k_gemm(const ushort_t* __restrict__ Ab, int lda,
                                              const ushort_t* __restrict__ Wb, int ldw,
                                              const float* __restrict__ bias,
                                              ushort_t* __restrict__ Yb, int ldy,
                                              int Kp, int ncols) {
    __shared__ ushort_t As[128 * 32];
    __shared__ ushort_t Bs[128 * 32];
    int tid = threadIdx.x;
    int lane = tid & 63, wv = tid >> 6;
    int bm = blockIdx.x * 128, bn = blockIdx.y * 128;
    int r = lane & 15, g4 = lane >> 4;
    int wr = (wv >> 1) * 64, wc = (wv & 1) * 64;

    f32x4 acc[4][4] = {};
    for (int k0 = 0; k0 < Kp; k0 += 32) {
#pragma unroll
        for (int ci = 0; ci < 2; ++ci) {
            int L = (wv * 2 + ci) * 1024 + lane * 16;
            int row = L >> 6, kb = L & 63;
            const char* ga = (const char*)Ab + ((size_t)(bm + row) * lda + k0) * 2 + kb;
            llds16(ga, (char*)As + (wv * 2 + ci) * 1024);
            const char* gb = (const char*)Wb + ((size_t)(bn + row) * ldw + k0) * 2 + kb;
            llds16(gb, (char*)Bs + (wv * 2 + ci) * 1024);
        }
        __syncthreads();
        bf16x8 af[4], bfr[4];
#pragma unroll
        for (int m = 0; m < 4; ++m)
            af[m] = *reinterpret_cast<const bf16x8*>((const char*)As + (wr + m * 16 + r) * 64 + g4 * 16);
#pragma unroll
        for (int n2 = 0; n2 < 4; ++n2)
            bfr[n2] = *reinterpret_cast<const bf16x8*>((const char*)Bs + (wc + n2 * 16 + r) * 64 + g4 * 16);
#pragma unroll
        for (int m = 0; m < 4; ++m)
#pragma unroll
            for (int n2 = 0; n2 < 4; ++n2)
                acc[m][n2] = __builtin_amdgcn_mfma_f32_16x16x32_bf16(af[m], bfr[n2], acc[m][n2], 0, 0, 0);
        __syncthreads();
    }
#pragma unroll
    for (int n2 = 0; n2 < 4; ++n2) {
        int col = bn + wc + n2 * 16 + r;
        if (col >= ncols) continue;
        float bv = bias[col];
#pragma unroll
        for (int m = 0; m < 4; ++m) {
#pragma unroll
            for (int j = 0; j < 4; ++j) {
                int row = bm + wr + m * 16 + g4 * 4 + j;
                Yb[(size_t)row * ldy + col] = f2bf(acc[m][n2][j] + bv);
            }
        }
    }
}

// ---------- Epilogue: radial-collapsed chain, 1 row per 64-thread block ----------
template <int NCP>
__global__ __launch_bounds__(64) void k_ep(const ushort_t* __restrict__ Y, int ldy,
                                           ushort_t* __restrict__ out, int ldo, int N) {
    constexpr int CH = NCP / 128;
    int i = blockIdx.x, t = threadIdx.x;
    const ushort_t* yr = Y + (size_t)i * ldy;
    float y[2 * CH], ym[2 * CH];
#pragma unroll
    for (int c = 0; c < CH; ++c) {
        ushort2 v = *reinterpret_cast<const ushort2*>(yr + c * 128 + 2 * t);
        y[2 * c] = bf2f(v.x);
        y[2 * c + 1] = bf2f(v.y);
    }
    if (t == 63) y[2 * CH - 1] = 0.f;  // pad column
    float s1l = 0.f, spl = 0.f;
#pragma unroll
    for (int q = 0; q < 2 * CH; ++q) {
        s1l += y[q] * y[q];
        ym[q] = fmaxf(y[q], 0.f);
        spl += ym[q] * ym[q];
    }
#pragma unroll
    for (int off = 32; off; off >>= 1) {
        s1l += __shfl_xor(s1l, off, 64);
        spl += __shfl_xor(spl, off, 64);
    }
    float s1 = s1l, sp = spl;
    bool allz = (s1 == 0.0f);
    float n1 = sqrtf(fmaxf(s1 + EPSF, 1e-6f));
    float fac1 = fsinh(fminf(n1, 50.f)) / n1;
    float S2 = allz ? 0.f : fac1 * fac1 * s1;
    float first1 = allz ? 0.f : sqrtf(1.f + S2);
    float dist = arcosh_f(first1 + EPSF);
    float rs = dist / sqrtf(S2 + EPSF);
    float coef1 = allz ? 0.f : rs * fac1;
    float S3 = coef1 * coef1 * sp;
    float n2 = sqrtf(fmaxf(S3 + EPSF, 1e-6f));
    float fac2 = fsinh(fminf(n2, 50.f)) / n2;
    float S4 = fac2 * fac2 * S3;
    float first2 = sqrtf(1.f + S4);
    float dist2 = arcosh_f(first2 + EPSF);
    float C = dist2 / sqrtf(S4 + EPSF) * fac2 * coef1;
    ushort_t* orow = out + (size_t)i * ldo;
#pragma unroll
    for (int c = 0; c < CH; ++c) {
        ushort2 o;
        o.x = f2bf(C * ym[2 * c]);
        o.y = f2bf(C * ym[2 * c + 1]);
        *reinterpret_cast<ushort2*>(orow + c * 128 + 2 * t) = o;
    }
}

// ---------- mean partials with fused per-row coefficient (layer-3 epilogue) ----------
// For each row: s1 = sum y^2, sp = sum relu(y)^2 (block reduce over 3 waves),
// C = radial-collapsed chain; accumulate C*relu(y). Deterministic.
__global__ __launch_bounds__(192) void k_mean(const ushort_t* __restrict__ Y,
                                              float* __restrict__ partials, int N, int chunk) {
    __shared__ float sred[8];
    int b = blockIdx.x;
    int t = threadIdx.x;
    int wv = t >> 6, lane = t & 63;
    int lo = b * chunk;
    int hi = lo + chunk; if (hi > N) hi = N;
    bool lastpair = (t == 191);     // col 383 is pad -> exclude
    float a0 = 0.f, a1 = 0.f;
    const ushort_t* p = Y + (size_t)lo * 384 + 2 * t;
    for (int n = lo; n < hi; ++n, p += 384) {
        ushort2 v = *reinterpret_cast<const ushort2*>(p);
        float y0 = bf2f(v.x);
        float y1 = lastpair ? 0.f : bf2f(v.y);
        float m0 = fmaxf(y0, 0.f), m1 = fmaxf(y1, 0.f);
        float s1l = y0 * y0 + y1 * y1;
        float spl = m0 * m0 + m1 * m1;
#pragma unroll
        for (int off = 32; off; off >>= 1) {
            s1l += __shfl_xor(s1l, off, 64);
            spl += __shfl_xor(spl, off, 64);
        }
        if (lane == 0) { sred[wv] = s1l; sred[4 + wv] = spl; }
        __syncthreads();
        float s1 = sred[0] + sred[1] + sred[2];
        float sp = sred[4] + sred[5] + sred[6];
        __syncthreads();
        bool allz = (s1 == 0.0f);
        float n1 = sqrtf(fmaxf(s1 + EPSF, 1e-6f));
        float fac1 = fsinh(fminf(n1, 50.f)) / n1;
        float S2 = allz ? 0.f : fac1 * fac1 * s1;
        float first1 = allz ? 0.f : sqrtf(1.f + S2);
        float dist = arcosh_f(first1 + EPSF);
        float rs = dist / sqrtf(S2 + EPSF);
        float coef1 = allz ? 0.f : rs * fac1;
        float S3 = coef1 * coef1 * sp;
        float n2 = sqrtf(fmaxf(S3 + EPSF, 1e-6f));
        float fac2 = fsinh(fminf(n2, 50.f)) / n2;
        float S4 = fac2 * fac2 * S3;
        float first2 = sqrtf(1.f + S4);
        float dist2 = arcosh_f(first2 + EPSF);
        float C = dist2 / sqrtf(S4 + EPSF) * fac2 * coef1;
        a0 += C * m0;
        a1 += C * m1;
    }
    float* orow = partials + (size_t)b * 384;
    orow[2 * t] = a0;
    orow[2 * t + 1] = a1;
}

// ---------- stage-2 mean reduce ----------
__global__ __launch_bounds__(256) void k_mred(const float* __restrict__ partials,
                                              float* __restrict__ hm, int nparts, int N) {
    __shared__ float sb[256];
    int j = blockIdx.x, t = threadIdx.x;
    float v = 0.f;
    for (int p = t; p < nparts; p += 256) v += partials[(size_t)p * 384 + j];
    sb[t] = v; __syncthreads();
    for (int st = 128; st > 0; st >>= 1) { if (t < st) sb[t] += sb[t + st]; __syncthreads(); }
    if (t == 0) hm[j] = sb[0] / (float)N;
}

// ---------- classifier head (libm precision retained; negligible cost) ----------
__global__ __launch_bounds__(64) void k_head(const float* __restrict__ hm,
                                             const float* __restrict__ Wc,
                                             const float* __restrict__ bc,
                                             float* __restrict__ dout, int ic, int oc) {
    int t = threadIdx.x;
    float h[6];
    float ss = 0.f;
#pragma unroll
    for (int c = 0; c < 6; ++c) {
        int j = t + 64 * c;
        h[c] = (j < ic) ? hm[j] : 0.f;
        ss += h[c] * h[c];
    }
    float ssum = wredsum(ss);
    float dist = logf(1.0f + EPSF + sqrtf((1.0f + EPSF) * (1.0f + EPSF) - 1.0f));
    float scl = dist / sqrtf(ssum + EPSF);
    float mxv[9];
#pragma unroll
    for (int o = 0; o < 9; ++o) {
        float p = 0.f;
        if (o < oc) {
#pragma unroll
            for (int c = 0; c < 6; ++c) {
                int j = t + 64 * c;
                if (j < ic) p += h[c] * Wc[(size_t)o * ic + j];
            }
        }
        float s = wredsum(p);
        mxv[o] = (o < oc) ? (scl * s + bc[o]) : 0.f;
    }
    if (t == 0) {
        float y[10], tt[10], lt[11], p[11], t3[11];
        float s1 = 0.f, sab = 0.f;
        for (int j = 0; j < 9; ++j) {
            y[j] = (j < oc) ? mxv[j] : 0.f;
            s1 += y[j] * y[j]; sab += fabsf(y[j]);
        }
        bool allz = (sab == 0.f);
        float n = sqrtf(fmaxf(s1 + EPSF, 1e-6f));
        float sh = sinhf(fminf(n, 50.f));
        float s2 = 0.f;
        for (int j = 0; j < oc; ++j) { tt[j] = allz ? 0.f : sh * y[j] / n; s2 += tt[j] * tt[j]; }
        float first = allz ? 0.f : sqrtf(1.f + s2);
        dout[0] = first;
        for (int j = 0; j < oc; ++j) dout[1 + j] = tt[j];
        float xx = fmaxf(first + EPSF, 1.0f + EPSF);
        float dist2 = logf(xx + sqrtf(xx * xx - 1.0f));
        float nrm2 = sqrtf(s2 + EPSF);
        lt[0] = 0.f;
        for (int j = 0; j < oc; ++j) lt[1 + j] = dist2 / nrm2 * tt[j];
        float m = lt[0];
        for (int j = 1; j <= oc; ++j) m = fmaxf(m, lt[j]);
        float es = 0.f;
        for (int j = 0; j <= oc; ++j) { p[j] = expf(lt[j] - m); es += p[j]; }
        for (int j = 0; j <= oc; ++j) p[j] /= es;
        p[0] = 0.f;
        float s3 = 0.f;
        for (int j = 1; j <= oc; ++j) s3 += p[j] * p[j];
        float n3 = sqrtf(fmaxf(s3 + EPSF, 1e-6f));
        float sh3 = sinhf(fminf(n3, 50.f));
        float s4 = 0.f;
        for (int j = 1; j <= oc; ++j) { t3[j] = sh3 * p[j] / n3; s4 += t3[j] * t3[j]; }
        dout[1 + oc] = sqrtf(1.f + s4);
        for (int j = 1; j <= oc; ++j) dout[1 + oc + j] = t3[j];
    }
}

extern "C" void kernel_launch(void* const* d_in, const int* in_sizes, int n_in,
                              void* d_out, int out_size, void* d_ws, size_t ws_size,
                              hipStream_t stream) {
    if (n_in < 10) return;
    const float* x   = (const float*)d_in[0];
    const int*   ei  = (const int*)d_in[1];
    const float* W0  = (const float*)d_in[2];
    const float* b0  = (const float*)d_in[3];
    const float* W1  = (const float*)d_in[4];
    const float* b1  = (const float*)d_in[5];
    const float* W2  = (const float*)d_in[6];
    const float* b2  = (const float*)d_in[7];
    const float* Wc  = (const float*)d_in[8];
    const float* bc  = (const float*)d_in[9];
    float* dout = (float*)d_out;

    int N = in_sizes[0] / 128;
    int E = in_sizes[1] / 2;
    int o1 = in_sizes[3];
    int i1 = in_sizes[2] / o1;
    int o2 = in_sizes[5];
    int i2 = in_sizes[4] / o2;
    int o3 = in_sizes[7];
    int i3 = in_sizes[6] / o3;
    int oc = in_sizes[9];
    int ic = in_sizes[8] / oc;

    int M_pad = ((N + 127) / 128) * 128;
    int Kp1 = ((i1 + 31) / 32) * 32;
    int Kp2 = ((i2 + 31) / 32) * 32;
    int Kp3 = ((i3 + 31) / 32) * 32;
    int Np1 = ((o1 + 127) / 128) * 128;
    int Np2 = ((o2 + 127) / 128) * 128;
    int Np3 = ((o3 + 127) / 128) * 128;

    const int* esrc = ei;
    const int* edst = ei + E;

    char* ws = (char*)d_ws;
    auto alloc = [&](size_t bytes) {
        char* p = ws;
        ws += (bytes + 511) & ~(size_t)511;
        return p;
    };
    ushort_t* Ab     = (ushort_t*)alloc((size_t)M_pad * 256 * 2);
    ushort_t* R      = (ushort_t*)alloc((size_t)M_pad * 384 * 2);
    ushort_t* Wb0    = (ushort_t*)alloc((size_t)Np1 * Kp1 * 2);
    ushort_t* Wb1    = (ushort_t*)alloc((size_t)Np2 * Kp2 * 2);
    ushort_t* Wb2    = (ushort_t*)alloc((size_t)Np3 * Kp3 * 2);
    int*      ebuf   = (int*)alloc((size_t)E * 4);
    int*      gcnt   = (int*)alloc((size_t)256 * 64 * 4);
    int*      bstart = (int*)alloc(128 * 4);
    int*      row_ptr= (int*)alloc((size_t)(N + 1) * 4);
    int*      srcl   = (int*)alloc((size_t)E * 4);
    float*    partials = (float*)alloc((size_t)2048 * 384 * 4);
    float*    hmbuf  = (float*)alloc(512 * 4);
    (void)ws_size;

    int NBKT = (N + 1023) >> 10;
    int EPB = 4096;
    int NBLK_E = (E + EPB - 1) / EPB;

    int t1 = Np1 * Kp1, t2 = Np2 * Kp2, t3 = Np3 * Kp3;
    k_convw3<<<dim3((t1 + t2 + t3 + 255) / 256), dim3(256), 0, stream>>>(
        W0, W1, W2, Wb0, Wb1, Wb2, o1, i1, Kp1, o2, i2, Kp2, o3, i3, Kp3, t1, t2, t3);
    // 1. log_map_zero(x) -> xt0 bf16
    k_log0<<<dim3(N), dim3(64), 0, stream>>>(x, (char*)Ab, N);
    // 2. bucket partition + per-bucket exact CSR (packed ebuf)
    k_c1<<<dim3(NBLK_E), dim3(256), 0, stream>>>(edst, gcnt, E, NBKT, EPB);
    k_c2<<<dim3(1), dim3(64), 0, stream>>>(gcnt, bstart, NBLK_E, NBKT);
    k_c3<<<dim3(NBLK_E), dim3(256), 0, stream>>>(esrc, edst, gcnt, ebuf, E, NBKT, EPB);
    k_c4<<<dim3(NBKT), dim3(256), 0, stream>>>(ebuf, bstart, row_ptr, srcl, N, NBKT, E);
    // 3. aggregate (8-way MLP gather) + collapsed epilogue -> A (bf16)
    k_agg<<<dim3(N), dim3(64), 0, stream>>>((const char*)Ab, row_ptr, srcl, Ab, N);
    // 4. layer 1
    k_gemm<<<dim3(M_pad / 128, Np1 / 128), dim3(256), 0, stream>>>(Ab, 256, Wb0, Kp1, b0, R, 128, Kp1, o1);
    k_ep<128><<<dim3(N), dim3(64), 0, stream>>>(R, 128, Ab, 256, N);
    // 5. layer 2
    k_gemm<<<dim3(M_pad / 128, Np2 / 128), dim3(256), 0, stream>>>(Ab, 256, Wb1, Kp2, b1, R, 256, Kp2, o2);
    k_ep<256><<<dim3(N), dim3(64), 0, stream>>>(R, 256, Ab, 256, N);
    // 6. layer 3: GEMM -> Y stays in R; epilogue fused into mean
    k_gemm<<<dim3(M_pad / 128, Np3 / 128), dim3(256), 0, stream>>>(Ab, 256, Wb2, Kp3, b2, R, 384, Kp3, o3);
    // 7. deterministic mean of ht = C * relu(Y), C computed in-kernel per row
    int NBLK = 2048;
    int chunk = (N + NBLK - 1) / NBLK;
    k_mean<<<dim3(NBLK), dim3(192), 0, stream>>>(R, partials, N, chunk);
    k_mred<<<dim3(383), dim3(256), 0, stream>>>(partials, hmbuf, NBLK, N);
    // 8. classifier head
    k_head<<<dim3(1), dim3(64), 0, stream>>>(hmbuf, Wc, bc, dout, ic, oc);
}

// Round 15
// 285.200 us; speedup vs baseline: 1.1567x; 1.1567x over previous
//
#include <hip/hip_runtime.h>
#include <math.h>

#define EPSF 1e-7f

typedef unsigned short ushort_t;
typedef __attribute__((ext_vector_type(8))) short bf16x8;
typedef __attribute__((ext_vector_type(4))) float f32x4;

// fast hardware transcendentals (v_exp_f32 / v_log_f32), ~2-4 ulp
__device__ __forceinline__ float fsinh(float x) { return 0.5f * (__expf(x) - __expf(-x)); }
__device__ __forceinline__ float arcosh_f(float x) {
    x = fmaxf(x, 1.0f + EPSF);
    return __logf(x + sqrtf(x * x - 1.0f));
}

__device__ __forceinline__ unsigned short f2bf(float f) {
    union { float f; unsigned u; } c; c.f = f;
    unsigned r = c.u + 0x7FFFu + ((c.u >> 16) & 1u);
    return (unsigned short)(r >> 16);
}
__device__ __forceinline__ float bf2f(unsigned short u) {
    union { unsigned u; float f; } c; c.u = ((unsigned)u) << 16;
    return c.f;
}

__device__ __forceinline__ float wredsum(float v) {
#pragma unroll
    for (int off = 32; off; off >>= 1) v += __shfl_xor(v, off, 64);
    return v;
}

__device__ __forceinline__ void llds16(const void* g, void* l) {
    __builtin_amdgcn_global_load_lds((const __attribute__((address_space(1))) unsigned int*)g,
                                     (__attribute__((address_space(3))) unsigned int*)l,
                                     16, 0, 0);
}

// ---------- K1: xt0 = log_map_zero(x) -> bf16, upper half of Abuf rows ----------
__global__ __launch_bounds__(64) void k_log0(const float* __restrict__ x,
                                             char* __restrict__ Abase, int N) {
    int i = blockIdx.x, t = threadIdx.x;
    float2 v = *reinterpret_cast<const float2*>(x + (size_t)i * 128 + 2 * t);
    float y0 = __shfl(v.x, 0, 64);
    float a0 = (t == 0) ? 0.f : v.x;
    float s = wredsum(a0 * a0 + v.y * v.y);
    float dist = arcosh_f(y0 + EPSF);
    float scl = dist / sqrtf(s + EPSF);
    ushort2 o;
    o.x = f2bf(scl * a0);
    o.y = f2bf(scl * v.y);
    *reinterpret_cast<ushort2*>(Abase + (size_t)i * 512 + 256 + 4 * t) = o;
}

// ---------- bucket partition: 1024-node buckets ----------
__global__ __launch_bounds__(256) void k_c1(const int* __restrict__ edst,
                                            int* __restrict__ gcnt,
                                            int E, int NBKT, int EPB) {
    __shared__ int cnt[64];
    int blk = blockIdx.x, t = threadIdx.x;
    for (int i = t; i < NBKT; i += 256) cnt[i] = 0;
    __syncthreads();
    int lo = blk * EPB, hi = min(lo + EPB, E);
    for (int e = lo + t; e < hi; e += 256) atomicAdd(&cnt[edst[e] >> 10], 1);
    __syncthreads();
    for (int i = t; i < NBKT; i += 256) gcnt[blk * NBKT + i] = cnt[i];
}

__global__ __launch_bounds__(64) void k_c2(int* __restrict__ gcnt,
                                           int* __restrict__ bstart, int NBLK, int NBKT) {
    __shared__ int sh[10816];
    __shared__ int tot[64];
    __shared__ int bs[65];
    int t = threadIdx.x;
    int total = NBLK * NBKT;
    for (int i = t; i < total; i += 64) sh[i] = gcnt[i];
    __syncthreads();
    if (t < NBKT) {
        int run = 0;
        for (int blk = 0; blk < NBLK; ++blk) {
            int idx = blk * NBKT + t;
            int c = sh[idx]; sh[idx] = run; run += c;
        }
        tot[t] = run;
    }
    __syncthreads();
    if (t == 0) {
        int r = 0;
        for (int b = 0; b < NBKT; ++b) { bs[b] = r; r += tot[b]; }
        bs[NBKT] = r;
    }
    __syncthreads();
    if (t < NBKT) {
        bstart[t] = bs[t];
        if (t == 0) bstart[NBKT] = bs[NBKT];
    }
    for (int i = t; i < total; i += 64) gcnt[i] = sh[i] + bs[i % NBKT];
}

// c3: place packed (dlo<<17 | src) into bucket regions (src < 2^17 since N = 50k)
__global__ __launch_bounds__(256) void k_c3(const int* __restrict__ esrc,
                                            const int* __restrict__ edst,
                                            const int* __restrict__ gcnt,
                                            int* __restrict__ ebuf,
                                            int E, int NBKT, int EPB) {
    __shared__ int cur[64];
    int blk = blockIdx.x, t = threadIdx.x;
    for (int i = t; i < NBKT; i += 256) cur[i] = 0;
    __syncthreads();
    int lo = blk * EPB, hi = min(lo + EPB, E);
    for (int e = lo + t; e < hi; e += 256) {
        int d = edst[e], s = esrc[e];
        int b = d >> 10;
        int r = atomicAdd(&cur[b], 1);
        ebuf[gcnt[blk * NBKT + b] + r] = ((d & 1023) << 17) | s;
    }
}

// ---------- c4: per-bucket exact CSR (L2-resident scatter), packed ebuf ----------
__global__ __launch_bounds__(256) void k_c4(const int* __restrict__ ebuf,
                                            const int* __restrict__ bstart,
                                            int* __restrict__ row_ptr,
                                            int* __restrict__ srcl,
                                            int N, int NBKT, int E) {
    __shared__ int cnt[1024];
    __shared__ int cur[1024];
    __shared__ int sb[256];
    int b = blockIdx.x, t = threadIdx.x;
    int lo = b << 10;
    int nn = min(1024, N - lo);
    for (int i = t; i < 1024; i += 256) cnt[i] = 0;
    __syncthreads();
    int es = bstart[b], ee = bstart[b + 1];
    for (int e = es + t; e < ee; e += 256) atomicAdd(&cnt[ebuf[e] >> 17], 1);
    __syncthreads();
    int base = t * 4;
    int c0 = cnt[base], c1 = cnt[base + 1], c2 = cnt[base + 2], c3 = cnt[base + 3];
    int ts = c0 + c1 + c2 + c3;
    sb[t] = ts; __syncthreads();
    for (int st = 1; st < 256; st <<= 1) {
        int v = (t >= st) ? sb[t - st] : 0;
        __syncthreads();
        sb[t] += v;
        __syncthreads();
    }
    int run = es + sb[t] - ts;
    int rp[4];
    rp[0] = run; rp[1] = run + c0; rp[2] = rp[1] + c1; rp[3] = rp[2] + c2;
#pragma unroll
    for (int q = 0; q < 4; ++q) {
        cur[base + q] = rp[q];
        if (base + q < nn) row_ptr[lo + base + q] = rp[q];
    }
    if (b == NBKT - 1 && t == 0) row_ptr[N] = E;
    __syncthreads();
    for (int e = es + t; e < ee; e += 256) {
        int p = ebuf[e];
        int r = atomicAdd(&cur[p >> 17], 1);
        srcl[r] = p & 0x1FFFF;
    }
}

// ---------- K3: agg (8-way unrolled gather) + radial-collapsed epilogue ----------
__global__ __launch_bounds__(64) void k_agg(const char* __restrict__ Abase,
                                            const int* __restrict__ row_ptr,
                                            const int* __restrict__ srcl,
                                            ushort_t* __restrict__ Ab, int N) {
    int i = blockIdx.x, t = threadIdx.x;
    const char* base = Abase + 256 + 4 * t;
    ushort2 sv = *reinterpret_cast<const ushort2*>(base + (size_t)i * 512);
    float p0[8], p1[8];
    p0[0] = bf2f(sv.x); p1[0] = bf2f(sv.y);
#pragma unroll
    for (int q = 1; q < 8; ++q) { p0[q] = 0.f; p1[q] = 0.f; }
    int b = row_ptr[i], e = row_ptr[i + 1];
    int k = b;
    for (; k + 8 <= e; k += 8) {
        int s[8];
#pragma unroll
        for (int q = 0; q < 8; ++q) s[q] = srcl[k + q];
        ushort2 v[8];
#pragma unroll
        for (int q = 0; q < 8; ++q)
            v[q] = *reinterpret_cast<const ushort2*>(base + (size_t)s[q] * 512);
#pragma unroll
        for (int q = 0; q < 8; ++q) { p0[q] += bf2f(v[q].x); p1[q] += bf2f(v[q].y); }
    }
    for (; k < e; ++k) {
        int s = srcl[k];
        ushort2 v = *reinterpret_cast<const ushort2*>(base + (size_t)s * 512);
        p0[0] += bf2f(v.x); p1[0] += bf2f(v.y);
    }
    float u0 = ((p0[0] + p0[1]) + (p0[2] + p0[3])) + ((p0[4] + p0[5]) + (p0[6] + p0[7]));
    float u1 = ((p1[0] + p1[1]) + (p1[2] + p1[3])) + ((p1[4] + p1[5]) + (p1[6] + p1[7]));
    if (t == 0) u0 = 0.f;
    float s1 = wredsum(u0 * u0 + u1 * u1);
    float n = sqrtf(fmaxf(s1 + EPSF, 1e-6f));
    float fac = fsinh(fminf(n, 50.f)) / n;
    float S2 = fac * fac * s1;
    float first = sqrtf(1.f + S2);
    float dist = arcosh_f(first + EPSF);
    float C = dist / sqrtf(S2 + EPSF) * fac;
    ushort2 o;
    o.x = f2bf(C * u0);
    o.y = f2bf(C * u1);
    *reinterpret_cast<ushort2*>(Ab + (size_t)i * 256 + 2 * t) = o;
}

// ---------- W conversion (all 3 layers, one launch) ----------
__global__ void k_convw3(const float* __restrict__ W0, const float* __restrict__ W1,
                         const float* __restrict__ W2,
                         ushort_t* __restrict__ Wb0, ushort_t* __restrict__ Wb1,
                         ushort_t* __restrict__ Wb2,
                         int o1, int i1, int Kp1, int o2, int i2, int Kp2,
                         int o3, int i3, int Kp3, int t1, int t2, int t3) {
    int idx = blockIdx.x * blockDim.x + threadIdx.x;
    const float* W; ushort_t* Wb; int ncols, K, Kp, shift;
    if (idx < t1) { W = W0; Wb = Wb0; ncols = o1; K = i1; Kp = Kp1; shift = 1; }
    else if (idx < t1 + t2) { idx -= t1; W = W1; Wb = Wb1; ncols = o2; K = i2; Kp = Kp2; shift = 0; }
    else if (idx < t1 + t2 + t3) { idx -= t1 + t2; W = W2; Wb = Wb2; ncols = o3; K = i3; Kp = Kp3; shift = 0; }
    else return;
    int o = idx / Kp, kk = idx - o * Kp;
    int ks = kk - shift;
    float v = 0.f;
    if (o < ncols && ks >= 0 && ks < K) v = W[(size_t)o * K + ks];
    Wb[idx] = f2bf(v);
}

// ---------- MFMA bf16 GEMM: Yb[M x ncols] = A @ W^T + bias, bf16 output ----------
__global__ __launch_bounds__(256) void k_gemm(const ushort_t* __restrict__ Ab, int lda,
                                              const ushort_t* __restrict__ Wb, int ldw,
                                              const float* __restrict__ bias,
                                              ushort_t* __restrict__ Yb, int ldy,
                                              int Kp, int ncols) {
    __shared__ ushort_t As[128 * 32];
    __shared__ ushort_t Bs[128 * 32];
    int tid = threadIdx.x;
    int lane = tid & 63, wv = tid >> 6;
    int bm = blockIdx.x * 128, bn = blockIdx.y * 128;
    int r = lane & 15, g4 = lane >> 4;
    int wr = (wv >> 1) * 64, wc = (wv & 1) * 64;

    f32x4 acc[4][4] = {};
    for (int k0 = 0; k0 < Kp; k0 += 32) {
#pragma unroll
        for (int ci = 0; ci < 2; ++ci) {
            int L = (wv * 2 + ci) * 1024 + lane * 16;
            int row = L >> 6, kb = L & 63;
            const char* ga = (const char*)Ab + ((size_t)(bm + row) * lda + k0) * 2 + kb;
            llds16(ga, (char*)As + (wv * 2 + ci) * 1024);
            const char* gb = (const char*)Wb + ((size_t)(bn + row) * ldw + k0) * 2 + kb;
            llds16(gb, (char*)Bs + (wv * 2 + ci) * 1024);
        }
        __syncthreads();
        bf16x8 af[4], bfr[4];
#pragma unroll
        for (int m = 0; m < 4; ++m)
            af[m] = *reinterpret_cast<const bf16x8*>((const char*)As + (wr + m * 16 + r) * 64 + g4 * 16);
#pragma unroll
        for (int n2 = 0; n2 < 4; ++n2)
            bfr[n2] = *reinterpret_cast<const bf16x8*>((const char*)Bs + (wc + n2 * 16 + r) * 64 + g4 * 16);
#pragma unroll
        for (int m = 0; m < 4; ++m)
#pragma unroll
            for (int n2 = 0; n2 < 4; ++n2)
                acc[m][n2] = __builtin_amdgcn_mfma_f32_16x16x32_bf16(af[m], bfr[n2], acc[m][n2], 0, 0, 0);
        __syncthreads();
    }
#pragma unroll
    for (int n2 = 0; n2 < 4; ++n2) {
        int col = bn + wc + n2 * 16 + r;
        if (col >= ncols) continue;
        float bv = bias[col];
#pragma unroll
        for (int m = 0; m < 4; ++m) {
#pragma unroll
            for (int j = 0; j < 4; ++j) {
                int row = bm + wr + m * 16 + g4 * 4 + j;
                Yb[(size_t)row * ldy + col] = f2bf(acc[m][n2][j] + bv);
            }
        }
    }
}

// ---------- Epilogue: radial-collapsed chain, 1 row per 64-thread block ----------
template <int NCP>
__global__ __launch_bounds__(64) void k_ep(const ushort_t* __restrict__ Y, int ldy,
                                           ushort_t* __restrict__ out, int ldo, int N) {
    constexpr int CH = NCP / 128;
    int i = blockIdx.x, t = threadIdx.x;
    const ushort_t* yr = Y + (size_t)i * ldy;
    float y[2 * CH], ym[2 * CH];
#pragma unroll
    for (int c = 0; c < CH; ++c) {
        ushort2 v = *reinterpret_cast<const ushort2*>(yr + c * 128 + 2 * t);
        y[2 * c] = bf2f(v.x);
        y[2 * c + 1] = bf2f(v.y);
    }
    if (t == 63) y[2 * CH - 1] = 0.f;  // pad column
    float s1l = 0.f, spl = 0.f;
#pragma unroll
    for (int q = 0; q < 2 * CH; ++q) {
        s1l += y[q] * y[q];
        ym[q] = fmaxf(y[q], 0.f);
        spl += ym[q] * ym[q];
    }
#pragma unroll
    for (int off = 32; off; off >>= 1) {
        s1l += __shfl_xor(s1l, off, 64);
        spl += __shfl_xor(spl, off, 64);
    }
    float s1 = s1l, sp = spl;
    bool allz = (s1 == 0.0f);
    float n1 = sqrtf(fmaxf(s1 + EPSF, 1e-6f));
    float fac1 = fsinh(fminf(n1, 50.f)) / n1;
    float S2 = allz ? 0.f : fac1 * fac1 * s1;
    float first1 = allz ? 0.f : sqrtf(1.f + S2);
    float dist = arcosh_f(first1 + EPSF);
    float rs = dist / sqrtf(S2 + EPSF);
    float coef1 = allz ? 0.f : rs * fac1;
    float S3 = coef1 * coef1 * sp;
    float n2 = sqrtf(fmaxf(S3 + EPSF, 1e-6f));
    float fac2 = fsinh(fminf(n2, 50.f)) / n2;
    float S4 = fac2 * fac2 * S3;
    float first2 = sqrtf(1.f + S4);
    float dist2 = arcosh_f(first2 + EPSF);
    float C = dist2 / sqrtf(S4 + EPSF) * fac2 * coef1;
    ushort_t* orow = out + (size_t)i * ldo;
#pragma unroll
    for (int c = 0; c < CH; ++c) {
        ushort2 o;
        o.x = f2bf(C * ym[2 * c]);
        o.y = f2bf(C * ym[2 * c + 1]);
        *reinterpret_cast<ushort2*>(orow + c * 128 + 2 * t) = o;
    }
}

// ---------- k_coef: layer-3 epilogue coefficient only (no ht write) ----------
__global__ __launch_bounds__(64) void k_coef(const ushort_t* __restrict__ Y, int ldy,
                                             float* __restrict__ coef, int N) {
    constexpr int CH = 3;
    int i = blockIdx.x, t = threadIdx.x;
    const ushort_t* yr = Y + (size_t)i * ldy;
    float y[2 * CH];
#pragma unroll
    for (int c = 0; c < CH; ++c) {
        ushort2 v = *reinterpret_cast<const ushort2*>(yr + c * 128 + 2 * t);
        y[2 * c] = bf2f(v.x);
        y[2 * c + 1] = bf2f(v.y);
    }
    if (t == 63) y[2 * CH - 1] = 0.f;  // pad column 383
    float s1l = 0.f, spl = 0.f;
#pragma unroll
    for (int q = 0; q < 2 * CH; ++q) {
        s1l += y[q] * y[q];
        float m = fmaxf(y[q], 0.f);
        spl += m * m;
    }
#pragma unroll
    for (int off = 32; off; off >>= 1) {
        s1l += __shfl_xor(s1l, off, 64);
        spl += __shfl_xor(spl, off, 64);
    }
    float s1 = s1l, sp = spl;
    bool allz = (s1 == 0.0f);
    float n1 = sqrtf(fmaxf(s1 + EPSF, 1e-6f));
    float fac1 = fsinh(fminf(n1, 50.f)) / n1;
    float S2 = allz ? 0.f : fac1 * fac1 * s1;
    float first1 = allz ? 0.f : sqrtf(1.f + S2);
    float dist = arcosh_f(first1 + EPSF);
    float rs = dist / sqrtf(S2 + EPSF);
    float coef1 = allz ? 0.f : rs * fac1;
    float S3 = coef1 * coef1 * sp;
    float n2 = sqrtf(fmaxf(S3 + EPSF, 1e-6f));
    float fac2 = fsinh(fminf(n2, 50.f)) / n2;
    float S4 = fac2 * fac2 * S3;
    float first2 = sqrtf(1.f + S4);
    float dist2 = arcosh_f(first2 + EPSF);
    float C = dist2 / sqrtf(S4 + EPSF) * fac2 * coef1;
    if (t == 0) coef[i] = C;
}

// ---------- mean partials: reads Y + coef, accumulates C*relu(y). deterministic ----------
__global__ __launch_bounds__(192) void k_mean(const ushort_t* __restrict__ Y,
                                              const float* __restrict__ coef,
                                              float* __restrict__ partials, int N, int chunk) {
    int b = blockIdx.x;
    int t = threadIdx.x;
    int lo = b * chunk;
    int hi = lo + chunk; if (hi > N) hi = N;
    bool lastpair = (t == 191);     // col 383 is pad (garbage) -> exclude
    float a0 = 0.f, a1 = 0.f;
    const ushort_t* p = Y + (size_t)lo * 384 + 2 * t;
    for (int n = lo; n < hi; ++n, p += 384) {
        float c = coef[n];
        ushort2 v = *reinterpret_cast<const ushort2*>(p);
        a0 += c * fmaxf(bf2f(v.x), 0.f);
        if (!lastpair) a1 += c * fmaxf(bf2f(v.y), 0.f);
    }
    float* orow = partials + (size_t)b * 384;
    orow[2 * t] = a0;
    orow[2 * t + 1] = a1;
}

// ---------- stage-2 mean reduce ----------
__global__ __launch_bounds__(256) void k_mred(const float* __restrict__ partials,
                                              float* __restrict__ hm, int nparts, int N) {
    __shared__ float sb[256];
    int j = blockIdx.x, t = threadIdx.x;
    float v = 0.f;
    for (int p = t; p < nparts; p += 256) v += partials[(size_t)p * 384 + j];
    sb[t] = v; __syncthreads();
    for (int st = 128; st > 0; st >>= 1) { if (t < st) sb[t] += sb[t + st]; __syncthreads(); }
    if (t == 0) hm[j] = sb[0] / (float)N;
}

// ---------- classifier head (libm precision retained; negligible cost) ----------
__global__ __launch_bounds__(64) void k_head(const float* __restrict__ hm,
                                             const float* __restrict__ Wc,
                                             const float* __restrict__ bc,
                                             float* __restrict__ dout, int ic, int oc) {
    int t = threadIdx.x;
    float h[6];
    float ss = 0.f;
#pragma unroll
    for (int c = 0; c < 6; ++c) {
        int j = t + 64 * c;
        h[c] = (j < ic) ? hm[j] : 0.f;
        ss += h[c] * h[c];
    }
    float ssum = wredsum(ss);
    float dist = logf(1.0f + EPSF + sqrtf((1.0f + EPSF) * (1.0f + EPSF) - 1.0f));
    float scl = dist / sqrtf(ssum + EPSF);
    float mxv[9];
#pragma unroll
    for (int o = 0; o < 9; ++o) {
        float p = 0.f;
        if (o < oc) {
#pragma unroll
            for (int c = 0; c < 6; ++c) {
                int j = t + 64 * c;
                if (j < ic) p += h[c] * Wc[(size_t)o * ic + j];
            }
        }
        float s = wredsum(p);
        mxv[o] = (o < oc) ? (scl * s + bc[o]) : 0.f;
    }
    if (t == 0) {
        float y[10], tt[10], lt[11], p[11], t3[11];
        float s1 = 0.f, sab = 0.f;
        for (int j = 0; j < 9; ++j) {
            y[j] = (j < oc) ? mxv[j] : 0.f;
            s1 += y[j] * y[j]; sab += fabsf(y[j]);
        }
        bool allz = (sab == 0.f);
        float n = sqrtf(fmaxf(s1 + EPSF, 1e-6f));
        float sh = sinhf(fminf(n, 50.f));
        float s2 = 0.f;
        for (int j = 0; j < oc; ++j) { tt[j] = allz ? 0.f : sh * y[j] / n; s2 += tt[j] * tt[j]; }
        float first = allz ? 0.f : sqrtf(1.f + s2);
        dout[0] = first;
        for (int j = 0; j < oc; ++j) dout[1 + j] = tt[j];
        float xx = fmaxf(first + EPSF, 1.0f + EPSF);
        float dist2 = logf(xx + sqrtf(xx * xx - 1.0f));
        float nrm2 = sqrtf(s2 + EPSF);
        lt[0] = 0.f;
        for (int j = 0; j < oc; ++j) lt[1 + j] = dist2 / nrm2 * tt[j];
        float m = lt[0];
        for (int j = 1; j <= oc; ++j) m = fmaxf(m, lt[j]);
        float es = 0.f;
        for (int j = 0; j <= oc; ++j) { p[j] = expf(lt[j] - m); es += p[j]; }
        for (int j = 0; j <= oc; ++j) p[j] /= es;
        p[0] = 0.f;
        float s3 = 0.f;
        for (int j = 1; j <= oc; ++j) s3 += p[j] * p[j];
        float n3 = sqrtf(fmaxf(s3 + EPSF, 1e-6f));
        float sh3 = sinhf(fminf(n3, 50.f));
        float s4 = 0.f;
        for (int j = 1; j <= oc; ++j) { t3[j] = sh3 * p[j] / n3; s4 += t3[j] * t3[j]; }
        dout[1 + oc] = sqrtf(1.f + s4);
        for (int j = 1; j <= oc; ++j) dout[1 + oc + j] = t3[j];
    }
}

extern "C" void kernel_launch(void* const* d_in, const int* in_sizes, int n_in,
                              void* d_out, int out_size, void* d_ws, size_t ws_size,
                              hipStream_t stream) {
    if (n_in < 10) return;
    const float* x   = (const float*)d_in[0];
    const int*   ei  = (const int*)d_in[1];
    const float* W0  = (const float*)d_in[2];
    const float* b0  = (const float*)d_in[3];
    const float* W1  = (const float*)d_in[4];
    const float* b1  = (const float*)d_in[5];
    const float* W2  = (const float*)d_in[6];
    const float* b2  = (const float*)d_in[7];
    const float* Wc  = (const float*)d_in[8];
    const float* bc  = (const float*)d_in[9];
    float* dout = (float*)d_out;

    int N = in_sizes[0] / 128;
    int E = in_sizes[1] / 2;
    int o1 = in_sizes[3];
    int i1 = in_sizes[2] / o1;
    int o2 = in_sizes[5];
    int i2 = in_sizes[4] / o2;
    int o3 = in_sizes[7];
    int i3 = in_sizes[6] / o3;
    int oc = in_sizes[9];
    int ic = in_sizes[8] / oc;

    int M_pad = ((N + 127) / 128) * 128;
    int Kp1 = ((i1 + 31) / 32) * 32;
    int Kp2 = ((i2 + 31) / 32) * 32;
    int Kp3 = ((i3 + 31) / 32) * 32;
    int Np1 = ((o1 + 127) / 128) * 128;
    int Np2 = ((o2 + 127) / 128) * 128;
    int Np3 = ((o3 + 127) / 128) * 128;

    const int* esrc = ei;
    const int* edst = ei + E;

    char* ws = (char*)d_ws;
    auto alloc = [&](size_t bytes) {
        char* p = ws;
        ws += (bytes + 511) & ~(size_t)511;
        return p;
    };
    ushort_t* Ab     = (ushort_t*)alloc((size_t)M_pad * 256 * 2);
    ushort_t* R      = (ushort_t*)alloc((size_t)M_pad * 384 * 2);
    ushort_t* Wb0    = (ushort_t*)alloc((size_t)Np1 * Kp1 * 2);
    ushort_t* Wb1    = (ushort_t*)alloc((size_t)Np2 * Kp2 * 2);
    ushort_t* Wb2    = (ushort_t*)alloc((size_t)Np3 * Kp3 * 2);
    int*      ebuf   = (int*)alloc((size_t)E * 4);
    int*      gcnt   = (int*)alloc((size_t)256 * 64 * 4);
    int*      bstart = (int*)alloc(128 * 4);
    int*      row_ptr= (int*)alloc((size_t)(N + 1) * 4);
    int*      srcl   = (int*)alloc((size_t)E * 4);
    float*    coefb  = (float*)alloc((size_t)N * 4);
    float*    partials = (float*)alloc((size_t)2048 * 384 * 4);
    float*    hmbuf  = (float*)alloc(512 * 4);
    (void)ws_size;

    int NBKT = (N + 1023) >> 10;
    int EPB = 4096;
    int NBLK_E = (E + EPB - 1) / EPB;

    int t1 = Np1 * Kp1, t2 = Np2 * Kp2, t3 = Np3 * Kp3;
    k_convw3<<<dim3((t1 + t2 + t3 + 255) / 256), dim3(256), 0, stream>>>(
        W0, W1, W2, Wb0, Wb1, Wb2, o1, i1, Kp1, o2, i2, Kp2, o3, i3, Kp3, t1, t2, t3);
    // 1. log_map_zero(x) -> xt0 bf16
    k_log0<<<dim3(N), dim3(64), 0, stream>>>(x, (char*)Ab, N);
    // 2. bucket partition + per-bucket exact CSR (packed ebuf)
    k_c1<<<dim3(NBLK_E), dim3(256), 0, stream>>>(edst, gcnt, E, NBKT, EPB);
    k_c2<<<dim3(1), dim3(64), 0, stream>>>(gcnt, bstart, NBLK_E, NBKT);
    k_c3<<<dim3(NBLK_E), dim3(256), 0, stream>>>(esrc, edst, gcnt, ebuf, E, NBKT, EPB);
    k_c4<<<dim3(NBKT), dim3(256), 0, stream>>>(ebuf, bstart, row_ptr, srcl, N, NBKT, E);
    // 3. aggregate (8-way MLP gather) + collapsed epilogue -> A (bf16)
    k_agg<<<dim3(N), dim3(64), 0, stream>>>((const char*)Ab, row_ptr, srcl, Ab, N);
    // 4. layer 1
    k_gemm<<<dim3(M_pad / 128, Np1 / 128), dim3(256), 0, stream>>>(Ab, 256, Wb0, Kp1, b0, R, 128, Kp1, o1);
    k_ep<128><<<dim3(N), dim3(64), 0, stream>>>(R, 128, Ab, 256, N);
    // 5. layer 2
    k_gemm<<<dim3(M_pad / 128, Np2 / 128), dim3(256), 0, stream>>>(Ab, 256, Wb1, Kp2, b1, R, 256, Kp2, o2);
    k_ep<256><<<dim3(N), dim3(64), 0, stream>>>(R, 256, Ab, 256, N);
    // 6. layer 3: GEMM -> Y stays in R; epilogue reduced to per-row coefficient
    k_gemm<<<dim3(M_pad / 128, Np3 / 128), dim3(256), 0, stream>>>(Ab, 256, Wb2, Kp3, b2, R, 384, Kp3, o3);
    k_coef<<<dim3(N), dim3(64), 0, stream>>>(R, 384, coefb, N);
    // 7. deterministic mean of ht = C * relu(Y), fused into stage-1
    int NBLK = 2048;
    int chunk = (N + NBLK - 1) / NBLK;
    k_mean<<<dim3(NBLK), dim3(192), 0, stream>>>(R, coefb, partials, N, chunk);
    k_mred<<<dim3(383), dim3(256), 0, stream>>>(partials, hmbuf, NBLK, N);
    // 8. classifier head
    k_head<<<dim3(1), dim3(64), 0, stream>>>(hmbuf, Wc, bc, dout, ic, oc);
}

// Round 16
// 265.326 us; speedup vs baseline: 1.2433x; 1.0749x over previous
//
#include <hip/hip_runtime.h>
#include <math.h>

#define EPSF 1e-7f

typedef unsigned short ushort_t;
typedef __attribute__((ext_vector_type(8))) short bf16x8;
typedef __attribute__((ext_vector_type(4))) float f32x4;

// fast hardware transcendentals (v_exp_f32 / v_log_f32), ~2-4 ulp
__device__ __forceinline__ float fsinh(float x) { return 0.5f * (__expf(x) - __expf(-x)); }
__device__ __forceinline__ float arcosh_f(float x) {
    x = fmaxf(x, 1.0f + EPSF);
    return __logf(x + sqrtf(x * x - 1.0f));
}

__device__ __forceinline__ unsigned short f2bf(float f) {
    union { float f; unsigned u; } c; c.f = f;
    unsigned r = c.u + 0x7FFFu + ((c.u >> 16) & 1u);
    return (unsigned short)(r >> 16);
}
__device__ __forceinline__ float bf2f(unsigned short u) {
    union { unsigned u; float f; } c; c.u = ((unsigned)u) << 16;
    return c.f;
}

__device__ __forceinline__ float wredsum(float v) {
#pragma unroll
    for (int off = 32; off; off >>= 1) v += __shfl_xor(v, off, 64);
    return v;
}

__device__ __forceinline__ void llds16(const void* g, void* l) {
    __builtin_amdgcn_global_load_lds((const __attribute__((address_space(1))) unsigned int*)g,
                                     (__attribute__((address_space(3))) unsigned int*)l,
                                     16, 0, 0);
}

// ---------- K1: xt0 = log_map_zero(x) -> bf16, upper half of Abuf rows ----------
__global__ __launch_bounds__(64) void k_log0(const float* __restrict__ x,
                                             char* __restrict__ Abase, int N) {
    int i = blockIdx.x, t = threadIdx.x;
    float2 v = *reinterpret_cast<const float2*>(x + (size_t)i * 128 + 2 * t);
    float y0 = __shfl(v.x, 0, 64);
    float a0 = (t == 0) ? 0.f : v.x;
    float s = wredsum(a0 * a0 + v.y * v.y);
    float dist = arcosh_f(y0 + EPSF);
    float scl = dist / sqrtf(s + EPSF);
    ushort2 o;
    o.x = f2bf(scl * a0);
    o.y = f2bf(scl * v.y);
    *reinterpret_cast<ushort2*>(Abase + (size_t)i * 512 + 256 + 4 * t) = o;
}

// ---------- bucket partition: 1024-node buckets ----------
__global__ __launch_bounds__(256) void k_c1(const int* __restrict__ edst,
                                            int* __restrict__ gcnt,
                                            int E, int NBKT, int EPB) {
    __shared__ int cnt[64];
    int blk = blockIdx.x, t = threadIdx.x;
    for (int i = t; i < NBKT; i += 256) cnt[i] = 0;
    __syncthreads();
    int lo = blk * EPB, hi = min(lo + EPB, E);
    for (int e = lo + t; e < hi; e += 256) atomicAdd(&cnt[edst[e] >> 10], 1);
    __syncthreads();
    for (int i = t; i < NBKT; i += 256) gcnt[blk * NBKT + i] = cnt[i];
}

__global__ __launch_bounds__(64) void k_c2(int* __restrict__ gcnt,
                                           int* __restrict__ bstart, int NBLK, int NBKT) {
    __shared__ int sh[10816];
    __shared__ int tot[64];
    __shared__ int bs[65];
    int t = threadIdx.x;
    int total = NBLK * NBKT;
    for (int i = t; i < total; i += 64) sh[i] = gcnt[i];
    __syncthreads();
    if (t < NBKT) {
        int run = 0;
        for (int blk = 0; blk < NBLK; ++blk) {
            int idx = blk * NBKT + t;
            int c = sh[idx]; sh[idx] = run; run += c;
        }
        tot[t] = run;
    }
    __syncthreads();
    if (t == 0) {
        int r = 0;
        for (int b = 0; b < NBKT; ++b) { bs[b] = r; r += tot[b]; }
        bs[NBKT] = r;
    }
    __syncthreads();
    if (t < NBKT) {
        bstart[t] = bs[t];
        if (t == 0) bstart[NBKT] = bs[NBKT];
    }
    for (int i = t; i < total; i += 64) gcnt[i] = sh[i] + bs[i % NBKT];
}

// c3: place packed (dlo<<17 | src) into bucket regions (src < 2^17 since N = 50k)
__global__ __launch_bounds__(256) void k_c3(const int* __restrict__ esrc,
                                            const int* __restrict__ edst,
                                            const int* __restrict__ gcnt,
                                            int* __restrict__ ebuf,
                                            int E, int NBKT, int EPB) {
    __shared__ int cur[64];
    int blk = blockIdx.x, t = threadIdx.x;
    for (int i = t; i < NBKT; i += 256) cur[i] = 0;
    __syncthreads();
    int lo = blk * EPB, hi = min(lo + EPB, E);
    for (int e = lo + t; e < hi; e += 256) {
        int d = edst[e], s = esrc[e];
        int b = d >> 10;
        int r = atomicAdd(&cur[b], 1);
        ebuf[gcnt[blk * NBKT + b] + r] = ((d & 1023) << 17) | s;
    }
}

// ---------- c4: per-bucket exact CSR, 1024 threads (1 node/thread scan) ----------
__global__ __launch_bounds__(1024) void k_c4(const int* __restrict__ ebuf,
                                             const int* __restrict__ bstart,
                                             int* __restrict__ row_ptr,
                                             int* __restrict__ srcl,
                                             int N, int NBKT, int E) {
    __shared__ int cnt[1024];
    __shared__ int cur[1024];
    __shared__ int wsum[17];
    int b = blockIdx.x, t = threadIdx.x;
    int lane = t & 63, wv = t >> 6;
    int lo = b << 10;
    int nn = min(1024, N - lo);
    cnt[t] = 0;
    __syncthreads();
    int es = bstart[b], ee = bstart[b + 1];
    for (int e = es + t; e < ee; e += 1024) atomicAdd(&cnt[ebuf[e] >> 17], 1);
    __syncthreads();
    int c = cnt[t];
    int sc = c;
#pragma unroll
    for (int off = 1; off < 64; off <<= 1) {
        int v = __shfl_up(sc, off, 64);
        if (lane >= off) sc += v;
    }
    if (lane == 63) wsum[wv + 1] = sc;
    if (t == 0) wsum[0] = 0;
    __syncthreads();
    if (t == 0) {
        for (int w = 1; w < 16; ++w) wsum[w + 1] += wsum[w];
    }
    __syncthreads();
    int rp = es + wsum[wv] + sc - c;   // exclusive prefix for node t
    cur[t] = rp;
    if (t < nn) row_ptr[lo + t] = rp;
    if (b == NBKT - 1 && t == 0) row_ptr[N] = E;
    __syncthreads();
    for (int e = es + t; e < ee; e += 1024) {
        int p = ebuf[e];
        int r = atomicAdd(&cur[p >> 17], 1);
        srcl[r] = p & 0x1FFFF;
    }
}

// ---------- K3: agg (8-way unrolled gather) + radial-collapsed epilogue ----------
__global__ __launch_bounds__(64) void k_agg(const char* __restrict__ Abase,
                                            const int* __restrict__ row_ptr,
                                            const int* __restrict__ srcl,
                                            ushort_t* __restrict__ Ab, int N) {
    int i = blockIdx.x, t = threadIdx.x;
    const char* base = Abase + 256 + 4 * t;
    ushort2 sv = *reinterpret_cast<const ushort2*>(base + (size_t)i * 512);
    float p0[8], p1[8];
    p0[0] = bf2f(sv.x); p1[0] = bf2f(sv.y);
#pragma unroll
    for (int q = 1; q < 8; ++q) { p0[q] = 0.f; p1[q] = 0.f; }
    int b = row_ptr[i], e = row_ptr[i + 1];
    int k = b;
    for (; k + 8 <= e; k += 8) {
        int s[8];
#pragma unroll
        for (int q = 0; q < 8; ++q) s[q] = srcl[k + q];
        ushort2 v[8];
#pragma unroll
        for (int q = 0; q < 8; ++q)
            v[q] = *reinterpret_cast<const ushort2*>(base + (size_t)s[q] * 512);
#pragma unroll
        for (int q = 0; q < 8; ++q) { p0[q] += bf2f(v[q].x); p1[q] += bf2f(v[q].y); }
    }
    for (; k < e; ++k) {
        int s = srcl[k];
        ushort2 v = *reinterpret_cast<const ushort2*>(base + (size_t)s * 512);
        p0[0] += bf2f(v.x); p1[0] += bf2f(v.y);
    }
    float u0 = ((p0[0] + p0[1]) + (p0[2] + p0[3])) + ((p0[4] + p0[5]) + (p0[6] + p0[7]));
    float u1 = ((p1[0] + p1[1]) + (p1[2] + p1[3])) + ((p1[4] + p1[5]) + (p1[6] + p1[7]));
    if (t == 0) u0 = 0.f;
    float s1 = wredsum(u0 * u0 + u1 * u1);
    float n = sqrtf(fmaxf(s1 + EPSF, 1e-6f));
    float fac = fsinh(fminf(n, 50.f)) / n;
    float S2 = fac * fac * s1;
    float first = sqrtf(1.f + S2);
    float dist = arcosh_f(first + EPSF);
    float C = dist / sqrtf(S2 + EPSF) * fac;
    ushort2 o;
    o.x = f2bf(C * u0);
    o.y = f2bf(C * u1);
    *reinterpret_cast<ushort2*>(Ab + (size_t)i * 256 + 2 * t) = o;
}

// ---------- W conversion (all 3 layers, one launch) ----------
__global__ void k_convw3(const float* __restrict__ W0, const float* __restrict__ W1,
                         const float* __restrict__ W2,
                         ushort_t* __restrict__ Wb0, ushort_t* __restrict__ Wb1,
                         ushort_t* __restrict__ Wb2,
                         int o1, int i1, int Kp1, int o2, int i2, int Kp2,
                         int o3, int i3, int Kp3, int t1, int t2, int t3) {
    int idx = blockIdx.x * blockDim.x + threadIdx.x;
    const float* W; ushort_t* Wb; int ncols, K, Kp, shift;
    if (idx < t1) { W = W0; Wb = Wb0; ncols = o1; K = i1; Kp = Kp1; shift = 1; }
    else if (idx < t1 + t2) { idx -= t1; W = W1; Wb = Wb1; ncols = o2; K = i2; Kp = Kp2; shift = 0; }
    else if (idx < t1 + t2 + t3) { idx -= t1 + t2; W = W2; Wb = Wb2; ncols = o3; K = i3; Kp = Kp3; shift = 0; }
    else return;
    int o = idx / Kp, kk = idx - o * Kp;
    int ks = kk - shift;
    float v = 0.f;
    if (o < ncols && ks >= 0 && ks < K) v = W[(size_t)o * K + ks];
    Wb[idx] = f2bf(v);
}

// ---------- MFMA bf16 GEMM: Yb[M x ncols] = A @ W^T + bias, bf16 output ----------
__global__ __launch_bounds__(256) void k_gemm(const ushort_t* __restrict__ Ab, int lda,
                                              const ushort_t* __restrict__ Wb, int ldw,
                                              const float* __restrict__ bias,
                                              ushort_t* __restrict__ Yb, int ldy,
                                              int Kp, int ncols) {
    __shared__ ushort_t As[128 * 32];
    __shared__ ushort_t Bs[128 * 32];
    int tid = threadIdx.x;
    int lane = tid & 63, wv = tid >> 6;
    int bm = blockIdx.x * 128, bn = blockIdx.y * 128;
    int r = lane & 15, g4 = lane >> 4;
    int wr = (wv >> 1) * 64, wc = (wv & 1) * 64;

    f32x4 acc[4][4] = {};
    for (int k0 = 0; k0 < Kp; k0 += 32) {
#pragma unroll
        for (int ci = 0; ci < 2; ++ci) {
            int L = (wv * 2 + ci) * 1024 + lane * 16;
            int row = L >> 6, kb = L & 63;
            const char* ga = (const char*)Ab + ((size_t)(bm + row) * lda + k0) * 2 + kb;
            llds16(ga, (char*)As + (wv * 2 + ci) * 1024);
            const char* gb = (const char*)Wb + ((size_t)(bn + row) * ldw + k0) * 2 + kb;
            llds16(gb, (char*)Bs + (wv * 2 + ci) * 1024);
        }
        __syncthreads();
        bf16x8 af[4], bfr[4];
#pragma unroll
        for (int m = 0; m < 4; ++m)
            af[m] = *reinterpret_cast<const bf16x8*>((const char*)As + (wr + m * 16 + r) * 64 + g4 * 16);
#pragma unroll
        for (int n2 = 0; n2 < 4; ++n2)
            bfr[n2] = *reinterpret_cast<const bf16x8*>((const char*)Bs + (wc + n2 * 16 + r) * 64 + g4 * 16);
#pragma unroll
        for (int m = 0; m < 4; ++m)
#pragma unroll
            for (int n2 = 0; n2 < 4; ++n2)
                acc[m][n2] = __builtin_amdgcn_mfma_f32_16x16x32_bf16(af[m], bfr[n2], acc[m][n2], 0, 0, 0);
        __syncthreads();
    }
#pragma unroll
    for (int n2 = 0; n2 < 4; ++n2) {
        int col = bn + wc + n2 * 16 + r;
        if (col >= ncols) continue;
        float bv = bias[col];
#pragma unroll
        for (int m = 0; m < 4; ++m) {
#pragma unroll
            for (int j = 0; j < 4; ++j) {
                int row = bm + wr + m * 16 + g4 * 4 + j;
                Yb[(size_t)row * ldy + col] = f2bf(acc[m][n2][j] + bv);
            }
        }
    }
}

// ---------- Epilogue: radial-collapsed chain, 1 row per 64-thread block ----------
template <int NCP>
__global__ __launch_bounds__(64) void k_ep(const ushort_t* __restrict__ Y, int ldy,
                                           ushort_t* __restrict__ out, int ldo, int N) {
    constexpr int CH = NCP / 128;
    int i = blockIdx.x, t = threadIdx.x;
    const ushort_t* yr = Y + (size_t)i * ldy;
    float y[2 * CH], ym[2 * CH];
#pragma unroll
    for (int c = 0; c < CH; ++c) {
        ushort2 v = *reinterpret_cast<const ushort2*>(yr + c * 128 + 2 * t);
        y[2 * c] = bf2f(v.x);
        y[2 * c + 1] = bf2f(v.y);
    }
    if (t == 63) y[2 * CH - 1] = 0.f;  // pad column
    float s1l = 0.f, spl = 0.f;
#pragma unroll
    for (int q = 0; q < 2 * CH; ++q) {
        s1l += y[q] * y[q];
        ym[q] = fmaxf(y[q], 0.f);
        spl += ym[q] * ym[q];
    }
#pragma unroll
    for (int off = 32; off; off >>= 1) {
        s1l += __shfl_xor(s1l, off, 64);
        spl += __shfl_xor(spl, off, 64);
    }
    float s1 = s1l, sp = spl;
    bool allz = (s1 == 0.0f);
    float n1 = sqrtf(fmaxf(s1 + EPSF, 1e-6f));
    float fac1 = fsinh(fminf(n1, 50.f)) / n1;
    float S2 = allz ? 0.f : fac1 * fac1 * s1;
    float first1 = allz ? 0.f : sqrtf(1.f + S2);
    float dist = arcosh_f(first1 + EPSF);
    float rs = dist / sqrtf(S2 + EPSF);
    float coef1 = allz ? 0.f : rs * fac1;
    float S3 = coef1 * coef1 * sp;
    float n2 = sqrtf(fmaxf(S3 + EPSF, 1e-6f));
    float fac2 = fsinh(fminf(n2, 50.f)) / n2;
    float S4 = fac2 * fac2 * S3;
    float first2 = sqrtf(1.f + S4);
    float dist2 = arcosh_f(first2 + EPSF);
    float C = dist2 / sqrtf(S4 + EPSF) * fac2 * coef1;
    ushort_t* orow = out + (size_t)i * ldo;
#pragma unroll
    for (int c = 0; c < CH; ++c) {
        ushort2 o;
        o.x = f2bf(C * ym[2 * c]);
        o.y = f2bf(C * ym[2 * c + 1]);
        *reinterpret_cast<ushort2*>(orow + c * 128 + 2 * t) = o;
    }
}

// ---------- k_coef: layer-3 epilogue coefficient only (no ht write) ----------
__global__ __launch_bounds__(64) void k_coef(const ushort_t* __restrict__ Y, int ldy,
                                             float* __restrict__ coef, int N) {
    constexpr int CH = 3;
    int i = blockIdx.x, t = threadIdx.x;
    const ushort_t* yr = Y + (size_t)i * ldy;
    float y[2 * CH];
#pragma unroll
    for (int c = 0; c < CH; ++c) {
        ushort2 v = *reinterpret_cast<const ushort2*>(yr + c * 128 + 2 * t);
        y[2 * c] = bf2f(v.x);
        y[2 * c + 1] = bf2f(v.y);
    }
    if (t == 63) y[2 * CH - 1] = 0.f;  // pad column 383
    float s1l = 0.f, spl = 0.f;
#pragma unroll
    for (int q = 0; q < 2 * CH; ++q) {
        s1l += y[q] * y[q];
        float m = fmaxf(y[q], 0.f);
        spl += m * m;
    }
#pragma unroll
    for (int off = 32; off; off >>= 1) {
        s1l += __shfl_xor(s1l, off, 64);
        spl += __shfl_xor(spl, off, 64);
    }
    float s1 = s1l, sp = spl;
    bool allz = (s1 == 0.0f);
    float n1 = sqrtf(fmaxf(s1 + EPSF, 1e-6f));
    float fac1 = fsinh(fminf(n1, 50.f)) / n1;
    float S2 = allz ? 0.f : fac1 * fac1 * s1;
    float first1 = allz ? 0.f : sqrtf(1.f + S2);
    float dist = arcosh_f(first1 + EPSF);
    float rs = dist / sqrtf(S2 + EPSF);
    float coef1 = allz ? 0.f : rs * fac1;
    float S3 = coef1 * coef1 * sp;
    float n2 = sqrtf(fmaxf(S3 + EPSF, 1e-6f));
    float fac2 = fsinh(fminf(n2, 50.f)) / n2;
    float S4 = fac2 * fac2 * S3;
    float first2 = sqrtf(1.f + S4);
    float dist2 = arcosh_f(first2 + EPSF);
    float C = dist2 / sqrtf(S4 + EPSF) * fac2 * coef1;
    if (t == 0) coef[i] = C;
}

// ---------- mean partials: reads Y + coef, accumulates C*relu(y). deterministic ----------
__global__ __launch_bounds__(192) void k_mean(const ushort_t* __restrict__ Y,
                                              const float* __restrict__ coef,
                                              float* __restrict__ partials, int N, int chunk) {
    int b = blockIdx.x;
    int t = threadIdx.x;
    int lo = b * chunk;
    int hi = lo + chunk; if (hi > N) hi = N;
    bool lastpair = (t == 191);     // col 383 is pad (garbage) -> exclude
    float a0 = 0.f, a1 = 0.f;
    const ushort_t* p = Y + (size_t)lo * 384 + 2 * t;
    for (int n = lo; n < hi; ++n, p += 384) {
        float c = coef[n];
        ushort2 v = *reinterpret_cast<const ushort2*>(p);
        a0 += c * fmaxf(bf2f(v.x), 0.f);
        if (!lastpair) a1 += c * fmaxf(bf2f(v.y), 0.f);
    }
    float* orow = partials + (size_t)b * 384;
    orow[2 * t] = a0;
    orow[2 * t + 1] = a1;
}

// ---------- stage-2 mean reduce ----------
__global__ __launch_bounds__(256) void k_mred(const float* __restrict__ partials,
                                              float* __restrict__ hm, int nparts, int N) {
    __shared__ float sb[256];
    int j = blockIdx.x, t = threadIdx.x;
    float v = 0.f;
    for (int p = t; p < nparts; p += 256) v += partials[(size_t)p * 384 + j];
    sb[t] = v; __syncthreads();
    for (int st = 128; st > 0; st >>= 1) { if (t < st) sb[t] += sb[t + st]; __syncthreads(); }
    if (t == 0) hm[j] = sb[0] / (float)N;
}

// ---------- classifier head (libm precision retained; negligible cost) ----------
__global__ __launch_bounds__(64) void k_head(const float* __restrict__ hm,
                                             const float* __restrict__ Wc,
                                             const float* __restrict__ bc,
                                             float* __restrict__ dout, int ic, int oc) {
    int t = threadIdx.x;
    float h[6];
    float ss = 0.f;
#pragma unroll
    for (int c = 0; c < 6; ++c) {
        int j = t + 64 * c;
        h[c] = (j < ic) ? hm[j] : 0.f;
        ss += h[c] * h[c];
    }
    float ssum = wredsum(ss);
    float dist = logf(1.0f + EPSF + sqrtf((1.0f + EPSF) * (1.0f + EPSF) - 1.0f));
    float scl = dist / sqrtf(ssum + EPSF);
    float mxv[9];
#pragma unroll
    for (int o = 0; o < 9; ++o) {
        float p = 0.f;
        if (o < oc) {
#pragma unroll
            for (int c = 0; c < 6; ++c) {
                int j = t + 64 * c;
                if (j < ic) p += h[c] * Wc[(size_t)o * ic + j];
            }
        }
        float s = wredsum(p);
        mxv[o] = (o < oc) ? (scl * s + bc[o]) : 0.f;
    }
    if (t == 0) {
        float y[10], tt[10], lt[11], p[11], t3[11];
        float s1 = 0.f, sab = 0.f;
        for (int j = 0; j < 9; ++j) {
            y[j] = (j < oc) ? mxv[j] : 0.f;
            s1 += y[j] * y[j]; sab += fabsf(y[j]);
        }
        bool allz = (sab == 0.f);
        float n = sqrtf(fmaxf(s1 + EPSF, 1e-6f));
        float sh = sinhf(fminf(n, 50.f));
        float s2 = 0.f;
        for (int j = 0; j < oc; ++j) { tt[j] = allz ? 0.f : sh * y[j] / n; s2 += tt[j] * tt[j]; }
        float first = allz ? 0.f : sqrtf(1.f + s2);
        dout[0] = first;
        for (int j = 0; j < oc; ++j) dout[1 + j] = tt[j];
        float xx = fmaxf(first + EPSF, 1.0f + EPSF);
        float dist2 = logf(xx + sqrtf(xx * xx - 1.0f));
        float nrm2 = sqrtf(s2 + EPSF);
        lt[0] = 0.f;
        for (int j = 0; j < oc; ++j) lt[1 + j] = dist2 / nrm2 * tt[j];
        float m = lt[0];
        for (int j = 1; j <= oc; ++j) m = fmaxf(m, lt[j]);
        float es = 0.f;
        for (int j = 0; j <= oc; ++j) { p[j] = expf(lt[j] - m); es += p[j]; }
        for (int j = 0; j <= oc; ++j) p[j] /= es;
        p[0] = 0.f;
        float s3 = 0.f;
        for (int j = 1; j <= oc; ++j) s3 += p[j] * p[j];
        float n3 = sqrtf(fmaxf(s3 + EPSF, 1e-6f));
        float sh3 = sinhf(fminf(n3, 50.f));
        float s4 = 0.f;
        for (int j = 1; j <= oc; ++j) { t3[j] = sh3 * p[j] / n3; s4 += t3[j] * t3[j]; }
        dout[1 + oc] = sqrtf(1.f + s4);
        for (int j = 1; j <= oc; ++j) dout[1 + oc + j] = t3[j];
    }
}

extern "C" void kernel_launch(void* const* d_in, const int* in_sizes, int n_in,
                              void* d_out, int out_size, void* d_ws, size_t ws_size,
                              hipStream_t stream) {
    if (n_in < 10) return;
    const float* x   = (const float*)d_in[0];
    const int*   ei  = (const int*)d_in[1];
    const float* W0  = (const float*)d_in[2];
    const float* b0  = (const float*)d_in[3];
    const float* W1  = (const float*)d_in[4];
    const float* b1  = (const float*)d_in[5];
    const float* W2  = (const float*)d_in[6];
    const float* b2  = (const float*)d_in[7];
    const float* Wc  = (const float*)d_in[8];
    const float* bc  = (const float*)d_in[9];
    float* dout = (float*)d_out;

    int N = in_sizes[0] / 128;
    int E = in_sizes[1] / 2;
    int o1 = in_sizes[3];
    int i1 = in_sizes[2] / o1;
    int o2 = in_sizes[5];
    int i2 = in_sizes[4] / o2;
    int o3 = in_sizes[7];
    int i3 = in_sizes[6] / o3;
    int oc = in_sizes[9];
    int ic = in_sizes[8] / oc;

    int M_pad = ((N + 127) / 128) * 128;
    int Kp1 = ((i1 + 31) / 32) * 32;
    int Kp2 = ((i2 + 31) / 32) * 32;
    int Kp3 = ((i3 + 31) / 32) * 32;
    int Np1 = ((o1 + 127) / 128) * 128;
    int Np2 = ((o2 + 127) / 128) * 128;
    int Np3 = ((o3 + 127) / 128) * 128;

    const int* esrc = ei;
    const int* edst = ei + E;

    char* ws = (char*)d_ws;
    auto alloc = [&](size_t bytes) {
        char* p = ws;
        ws += (bytes + 511) & ~(size_t)511;
        return p;
    };
    ushort_t* Ab     = (ushort_t*)alloc((size_t)M_pad * 256 * 2);
    ushort_t* R      = (ushort_t*)alloc((size_t)M_pad * 384 * 2);
    ushort_t* Wb0    = (ushort_t*)alloc((size_t)Np1 * Kp1 * 2);
    ushort_t* Wb1    = (ushort_t*)alloc((size_t)Np2 * Kp2 * 2);
    ushort_t* Wb2    = (ushort_t*)alloc((size_t)Np3 * Kp3 * 2);
    int*      ebuf   = (int*)alloc((size_t)E * 4);
    int*      gcnt   = (int*)alloc((size_t)256 * 64 * 4);
    int*      bstart = (int*)alloc(128 * 4);
    int*      row_ptr= (int*)alloc((size_t)(N + 1) * 4);
    int*      srcl   = (int*)alloc((size_t)E * 4);
    float*    coefb  = (float*)alloc((size_t)N * 4);
    float*    partials = (float*)alloc((size_t)2048 * 384 * 4);
    float*    hmbuf  = (float*)alloc(512 * 4);
    (void)ws_size;

    int NBKT = (N + 1023) >> 10;
    int EPB = 4096;
    int NBLK_E = (E + EPB - 1) / EPB;

    int t1 = Np1 * Kp1, t2 = Np2 * Kp2, t3 = Np3 * Kp3;
    k_convw3<<<dim3((t1 + t2 + t3 + 255) / 256), dim3(256), 0, stream>>>(
        W0, W1, W2, Wb0, Wb1, Wb2, o1, i1, Kp1, o2, i2, Kp2, o3, i3, Kp3, t1, t2, t3);
    // 1. log_map_zero(x) -> xt0 bf16
    k_log0<<<dim3(N), dim3(64), 0, stream>>>(x, (char*)Ab, N);
    // 2. bucket partition + per-bucket exact CSR (packed ebuf)
    k_c1<<<dim3(NBLK_E), dim3(256), 0, stream>>>(edst, gcnt, E, NBKT, EPB);
    k_c2<<<dim3(1), dim3(64), 0, stream>>>(gcnt, bstart, NBLK_E, NBKT);
    k_c3<<<dim3(NBLK_E), dim3(256), 0, stream>>>(esrc, edst, gcnt, ebuf, E, NBKT, EPB);
    k_c4<<<dim3(NBKT), dim3(1024), 0, stream>>>(ebuf, bstart, row_ptr, srcl, N, NBKT, E);
    // 3. aggregate (8-way MLP gather) + collapsed epilogue -> A (bf16)
    k_agg<<<dim3(N), dim3(64), 0, stream>>>((const char*)Ab, row_ptr, srcl, Ab, N);
    // 4. layer 1
    k_gemm<<<dim3(M_pad / 128, Np1 / 128), dim3(256), 0, stream>>>(Ab, 256, Wb0, Kp1, b0, R, 128, Kp1, o1);
    k_ep<128><<<dim3(N), dim3(64), 0, stream>>>(R, 128, Ab, 256, N);
    // 5. layer 2
    k_gemm<<<dim3(M_pad / 128, Np2 / 128), dim3(256), 0, stream>>>(Ab, 256, Wb1, Kp2, b1, R, 256, Kp2, o2);
    k_ep<256><<<dim3(N), dim3(64), 0, stream>>>(R, 256, Ab, 256, N);
    // 6. layer 3: GEMM -> Y stays in R; epilogue reduced to per-row coefficient
    k_gemm<<<dim3(M_pad / 128, Np3 / 128), dim3(256), 0, stream>>>(Ab, 256, Wb2, Kp3, b2, R, 384, Kp3, o3);
    k_coef<<<dim3(N), dim3(64), 0, stream>>>(R, 384, coefb, N);
    // 7. deterministic mean of ht = C * relu(Y), fused into stage-1
    int NBLK = 2048;
    int chunk = (N + NBLK - 1) / NBLK;
    k_mean<<<dim3(NBLK), dim3(192), 0, stream>>>(R, coefb, partials, N, chunk);
    k_mred<<<dim3(383), dim3(256), 0, stream>>>(partials, hmbuf, NBLK, N);
    // 8. classifier head
    k_head<<<dim3(1), dim3(64), 0, stream>>>(hmbuf, Wc, bc, dout, ic, oc);
}

// Round 17
// 245.073 us; speedup vs baseline: 1.3461x; 1.0826x over previous
//
#include <hip/hip_runtime.h>
#include <math.h>

#define EPSF 1e-7f

typedef unsigned short ushort_t;
typedef __attribute__((ext_vector_type(8))) short bf16x8;
typedef __attribute__((ext_vector_type(4))) float f32x4;

// fast hardware transcendentals (v_exp_f32 / v_log_f32), ~2-4 ulp
__device__ __forceinline__ float fsinh(float x) { return 0.5f * (__expf(x) - __expf(-x)); }
__device__ __forceinline__ float arcosh_f(float x) {
    x = fmaxf(x, 1.0f + EPSF);
    return __logf(x + sqrtf(x * x - 1.0f));
}

__device__ __forceinline__ unsigned short f2bf(float f) {
    union { float f; unsigned u; } c; c.f = f;
    unsigned r = c.u + 0x7FFFu + ((c.u >> 16) & 1u);
    return (unsigned short)(r >> 16);
}
__device__ __forceinline__ float bf2f(unsigned short u) {
    union { unsigned u; float f; } c; c.u = ((unsigned)u) << 16;
    return c.f;
}

__device__ __forceinline__ float wredsum(float v) {
#pragma unroll
    for (int off = 32; off; off >>= 1) v += __shfl_xor(v, off, 64);
    return v;
}

// radial-collapsed exp/log/relu/exp chain: returns C such that out = C*relu(y)
__device__ __forceinline__ float ep_coef(float s1, float sp) {
    bool allz = (s1 == 0.0f);
    float n1 = sqrtf(fmaxf(s1 + EPSF, 1e-6f));
    float fac1 = fsinh(fminf(n1, 50.f)) / n1;
    float S2 = allz ? 0.f : fac1 * fac1 * s1;
    float first1 = allz ? 0.f : sqrtf(1.f + S2);
    float dist = arcosh_f(first1 + EPSF);
    float rs = dist / sqrtf(S2 + EPSF);
    float coef1 = allz ? 0.f : rs * fac1;
    float S3 = coef1 * coef1 * sp;
    float n2 = sqrtf(fmaxf(S3 + EPSF, 1e-6f));
    float fac2 = fsinh(fminf(n2, 50.f)) / n2;
    float S4 = fac2 * fac2 * S3;
    float first2 = sqrtf(1.f + S4);
    float dist2 = arcosh_f(first2 + EPSF);
    return dist2 / sqrtf(S4 + EPSF) * fac2 * coef1;
}

__device__ __forceinline__ void llds16(const void* g, void* l) {
    __builtin_amdgcn_global_load_lds((const __attribute__((address_space(1))) unsigned int*)g,
                                     (__attribute__((address_space(3))) unsigned int*)l,
                                     16, 0, 0);
}

// ---------- K1: xt0 = log_map_zero(x) -> bf16, upper half of Abuf rows ----------
__global__ __launch_bounds__(64) void k_log0(const float* __restrict__ x,
                                             char* __restrict__ Abase, int N) {
    int i = blockIdx.x, t = threadIdx.x;
    float2 v = *reinterpret_cast<const float2*>(x + (size_t)i * 128 + 2 * t);
    float y0 = __shfl(v.x, 0, 64);
    float a0 = (t == 0) ? 0.f : v.x;
    float s = wredsum(a0 * a0 + v.y * v.y);
    float dist = arcosh_f(y0 + EPSF);
    float scl = dist / sqrtf(s + EPSF);
    ushort2 o;
    o.x = f2bf(scl * a0);
    o.y = f2bf(scl * v.y);
    *reinterpret_cast<ushort2*>(Abase + (size_t)i * 512 + 256 + 4 * t) = o;
}

// ---------- bucket partition: 1024-node buckets ----------
__global__ __launch_bounds__(256) void k_c1(const int* __restrict__ edst,
                                            int* __restrict__ gcnt,
                                            int E, int NBKT, int EPB) {
    __shared__ int cnt[64];
    int blk = blockIdx.x, t = threadIdx.x;
    for (int i = t; i < NBKT; i += 256) cnt[i] = 0;
    __syncthreads();
    int lo = blk * EPB, hi = min(lo + EPB, E);
    for (int e = lo + t; e < hi; e += 256) atomicAdd(&cnt[edst[e] >> 10], 1);
    __syncthreads();
    for (int i = t; i < NBKT; i += 256) gcnt[blk * NBKT + i] = cnt[i];
}

__global__ __launch_bounds__(64) void k_c2(int* __restrict__ gcnt,
                                           int* __restrict__ bstart, int NBLK, int NBKT) {
    __shared__ int sh[10816];
    __shared__ int tot[64];
    __shared__ int bs[65];
    int t = threadIdx.x;
    int total = NBLK * NBKT;
    for (int i = t; i < total; i += 64) sh[i] = gcnt[i];
    __syncthreads();
    if (t < NBKT) {
        int run = 0;
        for (int blk = 0; blk < NBLK; ++blk) {
            int idx = blk * NBKT + t;
            int c = sh[idx]; sh[idx] = run; run += c;
        }
        tot[t] = run;
    }
    __syncthreads();
    if (t == 0) {
        int r = 0;
        for (int b = 0; b < NBKT; ++b) { bs[b] = r; r += tot[b]; }
        bs[NBKT] = r;
    }
    __syncthreads();
    if (t < NBKT) {
        bstart[t] = bs[t];
        if (t == 0) bstart[NBKT] = bs[NBKT];
    }
    for (int i = t; i < total; i += 64) gcnt[i] = sh[i] + bs[i % NBKT];
}

// c3: place packed (dlo<<17 | src) into bucket regions (src < 2^17 since N = 50k)
__global__ __launch_bounds__(256) void k_c3(const int* __restrict__ esrc,
                                            const int* __restrict__ edst,
                                            const int* __restrict__ gcnt,
                                            int* __restrict__ ebuf,
                                            int E, int NBKT, int EPB) {
    __shared__ int cur[64];
    int blk = blockIdx.x, t = threadIdx.x;
    for (int i = t; i < NBKT; i += 256) cur[i] = 0;
    __syncthreads();
    int lo = blk * EPB, hi = min(lo + EPB, E);
    for (int e = lo + t; e < hi; e += 256) {
        int d = edst[e], s = esrc[e];
        int b = d >> 10;
        int r = atomicAdd(&cur[b], 1);
        ebuf[gcnt[blk * NBKT + b] + r] = ((d & 1023) << 17) | s;
    }
}

// ---------- c4: per-bucket exact CSR, 1024 threads (1 node/thread scan) ----------
__global__ __launch_bounds__(1024) void k_c4(const int* __restrict__ ebuf,
                                             const int* __restrict__ bstart,
                                             int* __restrict__ row_ptr,
                                             int* __restrict__ srcl,
                                             int N, int NBKT, int E) {
    __shared__ int cnt[1024];
    __shared__ int cur[1024];
    __shared__ int wsum[17];
    int b = blockIdx.x, t = threadIdx.x;
    int lane = t & 63, wv = t >> 6;
    int lo = b << 10;
    int nn = min(1024, N - lo);
    cnt[t] = 0;
    __syncthreads();
    int es = bstart[b], ee = bstart[b + 1];
    for (int e = es + t; e < ee; e += 1024) atomicAdd(&cnt[ebuf[e] >> 17], 1);
    __syncthreads();
    int c = cnt[t];
    int sc = c;
#pragma unroll
    for (int off = 1; off < 64; off <<= 1) {
        int v = __shfl_up(sc, off, 64);
        if (lane >= off) sc += v;
    }
    if (lane == 63) wsum[wv + 1] = sc;
    if (t == 0) wsum[0] = 0;
    __syncthreads();
    if (t == 0) {
        for (int w = 1; w < 16; ++w) wsum[w + 1] += wsum[w];
    }
    __syncthreads();
    int rp = es + wsum[wv] + sc - c;   // exclusive prefix for node t
    cur[t] = rp;
    if (t < nn) row_ptr[lo + t] = rp;
    if (b == NBKT - 1 && t == 0) row_ptr[N] = E;
    __syncthreads();
    for (int e = es + t; e < ee; e += 1024) {
        int p = ebuf[e];
        int r = atomicAdd(&cur[p >> 17], 1);
        srcl[r] = p & 0x1FFFF;
    }
}

// ---------- K3: agg (8-way unrolled gather) + radial-collapsed epilogue ----------
__global__ __launch_bounds__(64) void k_agg(const char* __restrict__ Abase,
                                            const int* __restrict__ row_ptr,
                                            const int* __restrict__ srcl,
                                            ushort_t* __restrict__ Ab, int N) {
    int i = blockIdx.x, t = threadIdx.x;
    const char* base = Abase + 256 + 4 * t;
    ushort2 sv = *reinterpret_cast<const ushort2*>(base + (size_t)i * 512);
    float p0[8], p1[8];
    p0[0] = bf2f(sv.x); p1[0] = bf2f(sv.y);
#pragma unroll
    for (int q = 1; q < 8; ++q) { p0[q] = 0.f; p1[q] = 0.f; }
    int b = row_ptr[i], e = row_ptr[i + 1];
    int k = b;
    for (; k + 8 <= e; k += 8) {
        int s[8];
#pragma unroll
        for (int q = 0; q < 8; ++q) s[q] = srcl[k + q];
        ushort2 v[8];
#pragma unroll
        for (int q = 0; q < 8; ++q)
            v[q] = *reinterpret_cast<const ushort2*>(base + (size_t)s[q] * 512);
#pragma unroll
        for (int q = 0; q < 8; ++q) { p0[q] += bf2f(v[q].x); p1[q] += bf2f(v[q].y); }
    }
    for (; k < e; ++k) {
        int s = srcl[k];
        ushort2 v = *reinterpret_cast<const ushort2*>(base + (size_t)s * 512);
        p0[0] += bf2f(v.x); p1[0] += bf2f(v.y);
    }
    float u0 = ((p0[0] + p0[1]) + (p0[2] + p0[3])) + ((p0[4] + p0[5]) + (p0[6] + p0[7]));
    float u1 = ((p1[0] + p1[1]) + (p1[2] + p1[3])) + ((p1[4] + p1[5]) + (p1[6] + p1[7]));
    if (t == 0) u0 = 0.f;
    float s1 = wredsum(u0 * u0 + u1 * u1);
    float n = sqrtf(fmaxf(s1 + EPSF, 1e-6f));
    float fac = fsinh(fminf(n, 50.f)) / n;
    float S2 = fac * fac * s1;
    float first = sqrtf(1.f + S2);
    float dist = arcosh_f(first + EPSF);
    float C = dist / sqrtf(S2 + EPSF) * fac;
    ushort2 o;
    o.x = f2bf(C * u0);
    o.y = f2bf(C * u1);
    *reinterpret_cast<ushort2*>(Ab + (size_t)i * 256 + 2 * t) = o;
}

// ---------- W conversion (all 3 layers, one launch) ----------
__global__ void k_convw3(const float* __restrict__ W0, const float* __restrict__ W1,
                         const float* __restrict__ W2,
                         ushort_t* __restrict__ Wb0, ushort_t* __restrict__ Wb1,
                         ushort_t* __restrict__ Wb2,
                         int o1, int i1, int Kp1, int o2, int i2, int Kp2,
                         int o3, int i3, int Kp3, int t1, int t2, int t3) {
    int idx = blockIdx.x * blockDim.x + threadIdx.x;
    const float* W; ushort_t* Wb; int ncols, K, Kp, shift;
    if (idx < t1) { W = W0; Wb = Wb0; ncols = o1; K = i1; Kp = Kp1; shift = 1; }
    else if (idx < t1 + t2) { idx -= t1; W = W1; Wb = Wb1; ncols = o2; K = i2; Kp = Kp2; shift = 0; }
    else if (idx < t1 + t2 + t3) { idx -= t1 + t2; W = W2; Wb = Wb2; ncols = o3; K = i3; Kp = Kp3; shift = 0; }
    else return;
    int o = idx / Kp, kk = idx - o * Kp;
    int ks = kk - shift;
    float v = 0.f;
    if (o < ncols && ks >= 0 && ks < K) v = W[(size_t)o * K + ks];
    Wb[idx] = f2bf(v);
}

// ---------- MFMA bf16 GEMM: Yb[M x ncols] = A @ W^T + bias, bf16 output ----------
__global__ __launch_bounds__(256) void k_gemm(const ushort_t* __restrict__ Ab, int lda,
                                              const ushort_t* __restrict__ Wb, int ldw,
                                              const float* __restrict__ bias,
                                              ushort_t* __restrict__ Yb, int ldy,
                                              int Kp, int ncols) {
    __shared__ ushort_t As[128 * 32];
    __shared__ ushort_t Bs[128 * 32];
    int tid = threadIdx.x;
    int lane = tid & 63, wv = tid >> 6;
    int bm = blockIdx.x * 128, bn = blockIdx.y * 128;
    int r = lane & 15, g4 = lane >> 4;
    int wr = (wv >> 1) * 64, wc = (wv & 1) * 64;

    f32x4 acc[4][4] = {};
    for (int k0 = 0; k0 < Kp; k0 += 32) {
#pragma unroll
        for (int ci = 0; ci < 2; ++ci) {
            int L = (wv * 2 + ci) * 1024 + lane * 16;
            int row = L >> 6, kb = L & 63;
            const char* ga = (const char*)Ab + ((size_t)(bm + row) * lda + k0) * 2 + kb;
            llds16(ga, (char*)As + (wv * 2 + ci) * 1024);
            const char* gb = (const char*)Wb + ((size_t)(bn + row) * ldw + k0) * 2 + kb;
            llds16(gb, (char*)Bs + (wv * 2 + ci) * 1024);
        }
        __syncthreads();
        bf16x8 af[4], bfr[4];
#pragma unroll
        for (int m = 0; m < 4; ++m)
            af[m] = *reinterpret_cast<const bf16x8*>((const char*)As + (wr + m * 16 + r) * 64 + g4 * 16);
#pragma unroll
        for (int n2 = 0; n2 < 4; ++n2)
            bfr[n2] = *reinterpret_cast<const bf16x8*>((const char*)Bs + (wc + n2 * 16 + r) * 64 + g4 * 16);
#pragma unroll
        for (int m = 0; m < 4; ++m)
#pragma unroll
            for (int n2 = 0; n2 < 4; ++n2)
                acc[m][n2] = __builtin_amdgcn_mfma_f32_16x16x32_bf16(af[m], bfr[n2], acc[m][n2], 0, 0, 0);
        __syncthreads();
    }
#pragma unroll
    for (int n2 = 0; n2 < 4; ++n2) {
        int col = bn + wc + n2 * 16 + r;
        if (col >= ncols) continue;
        float bv = bias[col];
#pragma unroll
        for (int m = 0; m < 4; ++m) {
#pragma unroll
            for (int j = 0; j < 4; ++j) {
                int row = bm + wr + m * 16 + g4 * 4 + j;
                Yb[(size_t)row * ldy + col] = f2bf(acc[m][n2][j] + bv);
            }
        }
    }
}

// ---------- fused layer-1 GEMM + epilogue: out = C_row * relu(A@W^T + b), in-place on Ab ----------
// Requires N-cols <= 128 (single block-column). Writes bf16 to Ab rows (lda 256), cols 0..127.
__global__ __launch_bounds__(256) void k_gemmf(const ushort_t* __restrict__ Ab, int lda,
                                               const ushort_t* __restrict__ Wb, int ldw,
                                               const float* __restrict__ bias,
                                               ushort_t* __restrict__ Out,
                                               int Kp, int ncols) {
    __shared__ ushort_t As[128 * 32];
    __shared__ ushort_t Bs[128 * 32];
    __shared__ float s1buf[2][128];
    __shared__ float spbuf[2][128];
    __shared__ float Cbuf[128];
    int tid = threadIdx.x;
    int lane = tid & 63, wv = tid >> 6;
    int bm = blockIdx.x * 128;
    int r = lane & 15, g4 = lane >> 4;
    int wr = (wv >> 1) * 64, wc = (wv & 1) * 64;
    int half = wv & 1;

    f32x4 acc[4][4] = {};
    for (int k0 = 0; k0 < Kp; k0 += 32) {
#pragma unroll
        for (int ci = 0; ci < 2; ++ci) {
            int L = (wv * 2 + ci) * 1024 + lane * 16;
            int row = L >> 6, kb = L & 63;
            const char* ga = (const char*)Ab + ((size_t)(bm + row) * lda + k0) * 2 + kb;
            llds16(ga, (char*)As + (wv * 2 + ci) * 1024);
            const char* gb = (const char*)Wb + ((size_t)(row) * ldw + k0) * 2 + kb;
            llds16(gb, (char*)Bs + (wv * 2 + ci) * 1024);
        }
        __syncthreads();
        bf16x8 af[4], bfr[4];
#pragma unroll
        for (int m = 0; m < 4; ++m)
            af[m] = *reinterpret_cast<const bf16x8*>((const char*)As + (wr + m * 16 + r) * 64 + g4 * 16);
#pragma unroll
        for (int n2 = 0; n2 < 4; ++n2)
            bfr[n2] = *reinterpret_cast<const bf16x8*>((const char*)Bs + (wc + n2 * 16 + r) * 64 + g4 * 16);
#pragma unroll
        for (int m = 0; m < 4; ++m)
#pragma unroll
            for (int n2 = 0; n2 < 4; ++n2)
                acc[m][n2] = __builtin_amdgcn_mfma_f32_16x16x32_bf16(af[m], bfr[n2], acc[m][n2], 0, 0, 0);
        __syncthreads();
    }
    // add bias, mask invalid cols, per-row partial reductions over this wave's 64 cols
    float bv[4];
#pragma unroll
    for (int n2 = 0; n2 < 4; ++n2) {
        int col = wc + n2 * 16 + r;
        bv[n2] = (col < ncols) ? bias[col] : 0.f;
    }
#pragma unroll
    for (int m = 0; m < 4; ++m) {
#pragma unroll
        for (int j = 0; j < 4; ++j) {
            float s1l = 0.f, spl = 0.f;
#pragma unroll
            for (int n2 = 0; n2 < 4; ++n2) {
                int col = wc + n2 * 16 + r;
                float y = (col < ncols) ? (acc[m][n2][j] + bv[n2]) : 0.f;
                acc[m][n2][j] = y;
                s1l += y * y;
                float ym = fmaxf(y, 0.f);
                spl += ym * ym;
            }
#pragma unroll
            for (int off = 1; off < 16; off <<= 1) {
                s1l += __shfl_xor(s1l, off, 64);
                spl += __shfl_xor(spl, off, 64);
            }
            if (r == 0) {
                int row = wr + m * 16 + g4 * 4 + j;
                s1buf[half][row] = s1l;
                spbuf[half][row] = spl;
            }
        }
    }
    __syncthreads();
    if (tid < 128) {
        float s1 = s1buf[0][tid] + s1buf[1][tid];
        float sp = spbuf[0][tid] + spbuf[1][tid];
        Cbuf[tid] = ep_coef(s1, sp);
    }
    __syncthreads();
#pragma unroll
    for (int m = 0; m < 4; ++m) {
#pragma unroll
        for (int j = 0; j < 4; ++j) {
            int rloc = wr + m * 16 + g4 * 4 + j;
            float C = Cbuf[rloc];
            size_t rowoff = (size_t)(bm + rloc) * 256;
#pragma unroll
            for (int n2 = 0; n2 < 4; ++n2) {
                int col = wc + n2 * 16 + r;
                Out[rowoff + col] = f2bf(C * fmaxf(acc[m][n2][j], 0.f));
            }
        }
    }
}

// ---------- Epilogue: radial-collapsed chain, 1 row per 64-thread block ----------
template <int NCP>
__global__ __launch_bounds__(64) void k_ep(const ushort_t* __restrict__ Y, int ldy,
                                           ushort_t* __restrict__ out, int ldo, int N) {
    constexpr int CH = NCP / 128;
    int i = blockIdx.x, t = threadIdx.x;
    const ushort_t* yr = Y + (size_t)i * ldy;
    float y[2 * CH], ym[2 * CH];
#pragma unroll
    for (int c = 0; c < CH; ++c) {
        ushort2 v = *reinterpret_cast<const ushort2*>(yr + c * 128 + 2 * t);
        y[2 * c] = bf2f(v.x);
        y[2 * c + 1] = bf2f(v.y);
    }
    if (t == 63) y[2 * CH - 1] = 0.f;  // pad column
    float s1l = 0.f, spl = 0.f;
#pragma unroll
    for (int q = 0; q < 2 * CH; ++q) {
        s1l += y[q] * y[q];
        ym[q] = fmaxf(y[q], 0.f);
        spl += ym[q] * ym[q];
    }
#pragma unroll
    for (int off = 32; off; off >>= 1) {
        s1l += __shfl_xor(s1l, off, 64);
        spl += __shfl_xor(spl, off, 64);
    }
    float C = ep_coef(s1l, spl);
    ushort_t* orow = out + (size_t)i * ldo;
#pragma unroll
    for (int c = 0; c < CH; ++c) {
        ushort2 o;
        o.x = f2bf(C * ym[2 * c]);
        o.y = f2bf(C * ym[2 * c + 1]);
        *reinterpret_cast<ushort2*>(orow + c * 128 + 2 * t) = o;
    }
}

// ---------- k_coef: layer-3 epilogue coefficient only (no ht write) ----------
__global__ __launch_bounds__(64) void k_coef(const ushort_t* __restrict__ Y, int ldy,
                                             float* __restrict__ coef, int N) {
    constexpr int CH = 3;
    int i = blockIdx.x, t = threadIdx.x;
    const ushort_t* yr = Y + (size_t)i * ldy;
    float y[2 * CH];
#pragma unroll
    for (int c = 0; c < CH; ++c) {
        ushort2 v = *reinterpret_cast<const ushort2*>(yr + c * 128 + 2 * t);
        y[2 * c] = bf2f(v.x);
        y[2 * c + 1] = bf2f(v.y);
    }
    if (t == 63) y[2 * CH - 1] = 0.f;  // pad column 383
    float s1l = 0.f, spl = 0.f;
#pragma unroll
    for (int q = 0; q < 2 * CH; ++q) {
        s1l += y[q] * y[q];
        float m = fmaxf(y[q], 0.f);
        spl += m * m;
    }
#pragma unroll
    for (int off = 32; off; off >>= 1) {
        s1l += __shfl_xor(s1l, off, 64);
        spl += __shfl_xor(spl, off, 64);
    }
    float C = ep_coef(s1l, spl);
    if (t == 0) coef[i] = C;
}

// ---------- mean partials: reads Y + coef, accumulates C*relu(y). deterministic ----------
__global__ __launch_bounds__(192) void k_mean(const ushort_t* __restrict__ Y,
                                              const float* __restrict__ coef,
                                              float* __restrict__ partials, int N, int chunk) {
    int b = blockIdx.x;
    int t = threadIdx.x;
    int lo = b * chunk;
    int hi = lo + chunk; if (hi > N) hi = N;
    bool lastpair = (t == 191);     // col 383 is pad (garbage) -> exclude
    float a0 = 0.f, a1 = 0.f;
    const ushort_t* p = Y + (size_t)lo * 384 + 2 * t;
    for (int n = lo; n < hi; ++n, p += 384) {
        float c = coef[n];
        ushort2 v = *reinterpret_cast<const ushort2*>(p);
        a0 += c * fmaxf(bf2f(v.x), 0.f);
        if (!lastpair) a1 += c * fmaxf(bf2f(v.y), 0.f);
    }
    float* orow = partials + (size_t)b * 384;
    orow[2 * t] = a0;
    orow[2 * t + 1] = a1;
}

// ---------- stage-2 mean reduce ----------
__global__ __launch_bounds__(256) void k_mred(const float* __restrict__ partials,
                                              float* __restrict__ hm, int nparts, int N) {
    __shared__ float sb[256];
    int j = blockIdx.x, t = threadIdx.x;
    float v = 0.f;
    for (int p = t; p < nparts; p += 256) v += partials[(size_t)p * 384 + j];
    sb[t] = v; __syncthreads();
    for (int st = 128; st > 0; st >>= 1) { if (t < st) sb[t] += sb[t + st]; __syncthreads(); }
    if (t == 0) hm[j] = sb[0] / (float)N;
}

// ---------- classifier head (libm precision retained; negligible cost) ----------
__global__ __launch_bounds__(64) void k_head(const float* __restrict__ hm,
                                             const float* __restrict__ Wc,
                                             const float* __restrict__ bc,
                                             float* __restrict__ dout, int ic, int oc) {
    int t = threadIdx.x;
    float h[6];
    float ss = 0.f;
#pragma unroll
    for (int c = 0; c < 6; ++c) {
        int j = t + 64 * c;
        h[c] = (j < ic) ? hm[j] : 0.f;
        ss += h[c] * h[c];
    }
    float ssum = wredsum(ss);
    float dist = logf(1.0f + EPSF + sqrtf((1.0f + EPSF) * (1.0f + EPSF) - 1.0f));
    float scl = dist / sqrtf(ssum + EPSF);
    float mxv[9];
#pragma unroll
    for (int o = 0; o < 9; ++o) {
        float p = 0.f;
        if (o < oc) {
#pragma unroll
            for (int c = 0; c < 6; ++c) {
                int j = t + 64 * c;
                if (j < ic) p += h[c] * Wc[(size_t)o * ic + j];
            }
        }
        float s = wredsum(p);
        mxv[o] = (o < oc) ? (scl * s + bc[o]) : 0.f;
    }
    if (t == 0) {
        float y[10], tt[10], lt[11], p[11], t3[11];
        float s1 = 0.f, sab = 0.f;
        for (int j = 0; j < 9; ++j) {
            y[j] = (j < oc) ? mxv[j] : 0.f;
            s1 += y[j] * y[j]; sab += fabsf(y[j]);
        }
        bool allz = (sab == 0.f);
        float n = sqrtf(fmaxf(s1 + EPSF, 1e-6f));
        float sh = sinhf(fminf(n, 50.f));
        float s2 = 0.f;
        for (int j = 0; j < oc; ++j) { tt[j] = allz ? 0.f : sh * y[j] / n; s2 += tt[j] * tt[j]; }
        float first = allz ? 0.f : sqrtf(1.f + s2);
        dout[0] = first;
        for (int j = 0; j < oc; ++j) dout[1 + j] = tt[j];
        float xx = fmaxf(first + EPSF, 1.0f + EPSF);
        float dist2 = logf(xx + sqrtf(xx * xx - 1.0f));
        float nrm2 = sqrtf(s2 + EPSF);
        lt[0] = 0.f;
        for (int j = 0; j < oc; ++j) lt[1 + j] = dist2 / nrm2 * tt[j];
        float m = lt[0];
        for (int j = 1; j <= oc; ++j) m = fmaxf(m, lt[j]);
        float es = 0.f;
        for (int j = 0; j <= oc; ++j) { p[j] = expf(lt[j] - m); es += p[j]; }
        for (int j = 0; j <= oc; ++j) p[j] /= es;
        p[0] = 0.f;
        float s3 = 0.f;
        for (int j = 1; j <= oc; ++j) s3 += p[j] * p[j];
        float n3 = sqrtf(fmaxf(s3 + EPSF, 1e-6f));
        float sh3 = sinhf(fminf(n3, 50.f));
        float s4 = 0.f;
        for (int j = 1; j <= oc; ++j) { t3[j] = sh3 * p[j] / n3; s4 += t3[j] * t3[j]; }
        dout[1 + oc] = sqrtf(1.f + s4);
        for (int j = 1; j <= oc; ++j) dout[1 + oc + j] = t3[j];
    }
}

extern "C" void kernel_launch(void* const* d_in, const int* in_sizes, int n_in,
                              void* d_out, int out_size, void* d_ws, size_t ws_size,
                              hipStream_t stream) {
    if (n_in < 10) return;
    const float* x   = (const float*)d_in[0];
    const int*   ei  = (const int*)d_in[1];
    const float* W0  = (const float*)d_in[2];
    const float* b0  = (const float*)d_in[3];
    const float* W1  = (const float*)d_in[4];
    const float* b1  = (const float*)d_in[5];
    const float* W2  = (const float*)d_in[6];
    const float* b2  = (const float*)d_in[7];
    const float* Wc  = (const float*)d_in[8];
    const float* bc  = (const float*)d_in[9];
    float* dout = (float*)d_out;

    int N = in_sizes[0] / 128;
    int E = in_sizes[1] / 2;
    int o1 = in_sizes[3];
    int i1 = in_sizes[2] / o1;
    int o2 = in_sizes[5];
    int i2 = in_sizes[4] / o2;
    int o3 = in_sizes[7];
    int i3 = in_sizes[6] / o3;
    int oc = in_sizes[9];
    int ic = in_sizes[8] / oc;

    int M_pad = ((N + 127) / 128) * 128;
    int Kp1 = ((i1 + 31) / 32) * 32;
    int Kp2 = ((i2 + 31) / 32) * 32;
    int Kp3 = ((i3 + 31) / 32) * 32;
    int Np1 = ((o1 + 127) / 128) * 128;
    int Np2 = ((o2 + 127) / 128) * 128;
    int Np3 = ((o3 + 127) / 128) * 128;

    const int* esrc = ei;
    const int* edst = ei + E;

    char* ws = (char*)d_ws;
    auto alloc = [&](size_t bytes) {
        char* p = ws;
        ws += (bytes + 511) & ~(size_t)511;
        return p;
    };
    ushort_t* Ab     = (ushort_t*)alloc((size_t)M_pad * 256 * 2);
    ushort_t* R      = (ushort_t*)alloc((size_t)M_pad * 384 * 2);
    ushort_t* Wb0    = (ushort_t*)alloc((size_t)Np1 * Kp1 * 2);
    ushort_t* Wb1    = (ushort_t*)alloc((size_t)Np2 * Kp2 * 2);
    ushort_t* Wb2    = (ushort_t*)alloc((size_t)Np3 * Kp3 * 2);
    int*      ebuf   = (int*)alloc((size_t)E * 4);
    int*      gcnt   = (int*)alloc((size_t)256 * 64 * 4);
    int*      bstart = (int*)alloc(128 * 4);
    int*      row_ptr= (int*)alloc((size_t)(N + 1) * 4);
    int*      srcl   = (int*)alloc((size_t)E * 4);
    float*    coefb  = (float*)alloc((size_t)N * 4);
    float*    partials = (float*)alloc((size_t)2048 * 384 * 4);
    float*    hmbuf  = (float*)alloc(512 * 4);
    (void)ws_size;

    int NBKT = (N + 1023) >> 10;
    int EPB = 4096;
    int NBLK_E = (E + EPB - 1) / EPB;

    int t1 = Np1 * Kp1, t2 = Np2 * Kp2, t3 = Np3 * Kp3;
    k_convw3<<<dim3((t1 + t2 + t3 + 255) / 256), dim3(256), 0, stream>>>(
        W0, W1, W2, Wb0, Wb1, Wb2, o1, i1, Kp1, o2, i2, Kp2, o3, i3, Kp3, t1, t2, t3);
    // 1. log_map_zero(x) -> xt0 bf16
    k_log0<<<dim3(N), dim3(64), 0, stream>>>(x, (char*)Ab, N);
    // 2. bucket partition + per-bucket exact CSR (packed ebuf)
    k_c1<<<dim3(NBLK_E), dim3(256), 0, stream>>>(edst, gcnt, E, NBKT, EPB);
    k_c2<<<dim3(1), dim3(64), 0, stream>>>(gcnt, bstart, NBLK_E, NBKT);
    k_c3<<<dim3(NBLK_E), dim3(256), 0, stream>>>(esrc, edst, gcnt, ebuf, E, NBKT, EPB);
    k_c4<<<dim3(NBKT), dim3(1024), 0, stream>>>(ebuf, bstart, row_ptr, srcl, N, NBKT, E);
    // 3. aggregate (8-way MLP gather) + collapsed epilogue -> A (bf16)
    k_agg<<<dim3(N), dim3(64), 0, stream>>>((const char*)Ab, row_ptr, srcl, Ab, N);
    // 4. layer 1: fused GEMM + epilogue, in-place on Ab (single block-column: Np1 == 128)
    k_gemmf<<<dim3(M_pad / 128), dim3(256), 0, stream>>>(Ab, 256, Wb0, Kp1, b0, Ab, Kp1, o1);
    // 5. layer 2
    k_gemm<<<dim3(M_pad / 128, Np2 / 128), dim3(256), 0, stream>>>(Ab, 256, Wb1, Kp2, b1, R, 256, Kp2, o2);
    k_ep<256><<<dim3(N), dim3(64), 0, stream>>>(R, 256, Ab, 256, N);
    // 6. layer 3: GEMM -> Y stays in R; epilogue reduced to per-row coefficient
    k_gemm<<<dim3(M_pad / 128, Np3 / 128), dim3(256), 0, stream>>>(Ab, 256, Wb2, Kp3, b2, R, 384, Kp3, o3);
    k_coef<<<dim3(N), dim3(64), 0, stream>>>(R, 384, coefb, N);
    // 7. deterministic mean of ht = C * relu(Y)
    int NBLK = 2048;
    int chunk = (N + NBLK - 1) / NBLK;
    k_mean<<<dim3(NBLK), dim3(192), 0, stream>>>(R, coefb, partials, N, chunk);
    k_mred<<<dim3(383), dim3(256), 0, stream>>>(partials, hmbuf, NBLK, N);
    // 8. classifier head
    k_head<<<dim3(1), dim3(64), 0, stream>>>(hmbuf, Wc, bc, dout, ic, oc);
}

// Round 18
// 213.847 us; speedup vs baseline: 1.5426x; 1.1460x over previous
//
#include <hip/hip_runtime.h>
#include <math.h>

#define EPSF 1e-7f

typedef unsigned short ushort_t;
typedef __attribute__((ext_vector_type(8))) short bf16x8;
typedef __attribute__((ext_vector_type(4))) float f32x4;

__device__ __forceinline__ float fsinh(float x) { return 0.5f * (__expf(x) - __expf(-x)); }
__device__ __forceinline__ float arcosh_f(float x) {
    x = fmaxf(x, 1.0f + EPSF);
    return __logf(x + sqrtf(x * x - 1.0f));
}

__device__ __forceinline__ unsigned short f2bf(float f) {
    union { float f; unsigned u; } c; c.f = f;
    unsigned r = c.u + 0x7FFFu + ((c.u >> 16) & 1u);
    return (unsigned short)(r >> 16);
}
__device__ __forceinline__ float bf2f(unsigned short u) {
    union { unsigned u; float f; } c; c.u = ((unsigned)u) << 16;
    return c.f;
}

__device__ __forceinline__ float wredsum(float v) {
#pragma unroll
    for (int off = 32; off; off >>= 1) v += __shfl_xor(v, off, 64);
    return v;
}

// radial-collapsed exp/log/relu/exp chain: returns C such that out = C*relu(y)
__device__ __forceinline__ float ep_coef(float s1, float sp) {
    bool allz = (s1 == 0.0f);
    float n1 = sqrtf(fmaxf(s1 + EPSF, 1e-6f));
    float fac1 = fsinh(fminf(n1, 50.f)) / n1;
    float S2 = allz ? 0.f : fac1 * fac1 * s1;
    float first1 = allz ? 0.f : sqrtf(1.f + S2);
    float dist = arcosh_f(first1 + EPSF);
    float rs = dist / sqrtf(S2 + EPSF);
    float coef1 = allz ? 0.f : rs * fac1;
    float S3 = coef1 * coef1 * sp;
    float n2 = sqrtf(fmaxf(S3 + EPSF, 1e-6f));
    float fac2 = fsinh(fminf(n2, 50.f)) / n2;
    float S4 = fac2 * fac2 * S3;
    float first2 = sqrtf(1.f + S4);
    float dist2 = arcosh_f(first2 + EPSF);
    return dist2 / sqrtf(S4 + EPSF) * fac2 * coef1;
}

__device__ __forceinline__ void llds16(const void* g, void* l) {
    __builtin_amdgcn_global_load_lds((const __attribute__((address_space(1))) unsigned int*)g,
                                     (__attribute__((address_space(3))) unsigned int*)l,
                                     16, 0, 0);
}

// ---------- K1: xt0 = log_map_zero(x) -> bf16, upper half of Abuf rows ----------
__global__ __launch_bounds__(64) void k_log0(const float* __restrict__ x,
                                             char* __restrict__ Abase, int N) {
    int i = blockIdx.x, t = threadIdx.x;
    float2 v = *reinterpret_cast<const float2*>(x + (size_t)i * 128 + 2 * t);
    float y0 = __shfl(v.x, 0, 64);
    float a0 = (t == 0) ? 0.f : v.x;
    float s = wredsum(a0 * a0 + v.y * v.y);
    float dist = arcosh_f(y0 + EPSF);
    float scl = dist / sqrtf(s + EPSF);
    ushort2 o;
    o.x = f2bf(scl * a0);
    o.y = f2bf(scl * v.y);
    *reinterpret_cast<ushort2*>(Abase + (size_t)i * 512 + 256 + 4 * t) = o;
}

// ---------- bucket partition: 1024-node buckets ----------
__global__ __launch_bounds__(256) void k_c1(const int* __restrict__ edst,
                                            int* __restrict__ gcnt,
                                            int E, int NBKT, int EPB) {
    __shared__ int cnt[64];
    int blk = blockIdx.x, t = threadIdx.x;
    for (int i = t; i < NBKT; i += 256) cnt[i] = 0;
    __syncthreads();
    int lo = blk * EPB, hi = min(lo + EPB, E);
    for (int e = lo + t; e < hi; e += 256) atomicAdd(&cnt[edst[e] >> 10], 1);
    __syncthreads();
    for (int i = t; i < NBKT; i += 256) gcnt[blk * NBKT + i] = cnt[i];
}

__global__ __launch_bounds__(64) void k_c2(int* __restrict__ gcnt,
                                           int* __restrict__ bstart, int NBLK, int NBKT) {
    __shared__ int sh[10816];
    __shared__ int tot[64];
    __shared__ int bs[65];
    int t = threadIdx.x;
    int total = NBLK * NBKT;
    for (int i = t; i < total; i += 64) sh[i] = gcnt[i];
    __syncthreads();
    if (t < NBKT) {
        int run = 0;
        for (int blk = 0; blk < NBLK; ++blk) {
            int idx = blk * NBKT + t;
            int c = sh[idx]; sh[idx] = run; run += c;
        }
        tot[t] = run;
    }
    __syncthreads();
    if (t == 0) {
        int r = 0;
        for (int b = 0; b < NBKT; ++b) { bs[b] = r; r += tot[b]; }
        bs[NBKT] = r;
    }
    __syncthreads();
    if (t < NBKT) {
        bstart[t] = bs[t];
        if (t == 0) bstart[NBKT] = bs[NBKT];
    }
    for (int i = t; i < total; i += 64) gcnt[i] = sh[i] + bs[i % NBKT];
}

// c3: place packed (dlo<<17 | src) into bucket regions
__global__ __launch_bounds__(256) void k_c3(const int* __restrict__ esrc,
                                            const int* __restrict__ edst,
                                            const int* __restrict__ gcnt,
                                            int* __restrict__ ebuf,
                                            int E, int NBKT, int EPB) {
    __shared__ int cur[64];
    int blk = blockIdx.x, t = threadIdx.x;
    for (int i = t; i < NBKT; i += 256) cur[i] = 0;
    __syncthreads();
    int lo = blk * EPB, hi = min(lo + EPB, E);
    for (int e = lo + t; e < hi; e += 256) {
        int d = edst[e], s = esrc[e];
        int b = d >> 10;
        int r = atomicAdd(&cur[b], 1);
        ebuf[gcnt[blk * NBKT + b] + r] = ((d & 1023) << 17) | s;
    }
}

// ---------- c4: per-bucket exact CSR, 1024 threads ----------
__global__ __launch_bounds__(1024) void k_c4(const int* __restrict__ ebuf,
                                             const int* __restrict__ bstart,
                                             int* __restrict__ row_ptr,
                                             int* __restrict__ srcl,
                                             int N, int NBKT, int E) {
    __shared__ int cnt[1024];
    __shared__ int cur[1024];
    __shared__ int wsum[17];
    int b = blockIdx.x, t = threadIdx.x;
    int lane = t & 63, wv = t >> 6;
    int lo = b << 10;
    int nn = min(1024, N - lo);
    cnt[t] = 0;
    __syncthreads();
    int es = bstart[b], ee = bstart[b + 1];
    for (int e = es + t; e < ee; e += 1024) atomicAdd(&cnt[ebuf[e] >> 17], 1);
    __syncthreads();
    int c = cnt[t];
    int sc = c;
#pragma unroll
    for (int off = 1; off < 64; off <<= 1) {
        int v = __shfl_up(sc, off, 64);
        if (lane >= off) sc += v;
    }
    if (lane == 63) wsum[wv + 1] = sc;
    if (t == 0) wsum[0] = 0;
    __syncthreads();
    if (t == 0) {
        for (int w = 1; w < 16; ++w) wsum[w + 1] += wsum[w];
    }
    __syncthreads();
    int rp = es + wsum[wv] + sc - c;
    cur[t] = rp;
    if (t < nn) row_ptr[lo + t] = rp;
    if (b == NBKT - 1 && t == 0) row_ptr[N] = E;
    __syncthreads();
    for (int e = es + t; e < ee; e += 1024) {
        int p = ebuf[e];
        int r = atomicAdd(&cur[p >> 17], 1);
        srcl[r] = p & 0x1FFFF;
    }
}

// ---------- K3: agg (8-way unrolled gather) + radial-collapsed epilogue ----------
__global__ __launch_bounds__(64) void k_agg(const char* __restrict__ Abase,
                                            const int* __restrict__ row_ptr,
                                            const int* __restrict__ srcl,
                                            ushort_t* __restrict__ Ab, int N) {
    int i = blockIdx.x, t = threadIdx.x;
    const char* base = Abase + 256 + 4 * t;
    ushort2 sv = *reinterpret_cast<const ushort2*>(base + (size_t)i * 512);
    float p0[8], p1[8];
    p0[0] = bf2f(sv.x); p1[0] = bf2f(sv.y);
#pragma unroll
    for (int q = 1; q < 8; ++q) { p0[q] = 0.f; p1[q] = 0.f; }
    int b = row_ptr[i], e = row_ptr[i + 1];
    int k = b;
    for (; k + 8 <= e; k += 8) {
        int s[8];
#pragma unroll
        for (int q = 0; q < 8; ++q) s[q] = srcl[k + q];
        ushort2 v[8];
#pragma unroll
        for (int q = 0; q < 8; ++q)
            v[q] = *reinterpret_cast<const ushort2*>(base + (size_t)s[q] * 512);
#pragma unroll
        for (int q = 0; q < 8; ++q) { p0[q] += bf2f(v[q].x); p1[q] += bf2f(v[q].y); }
    }
    for (; k < e; ++k) {
        int s = srcl[k];
        ushort2 v = *reinterpret_cast<const ushort2*>(base + (size_t)s * 512);
        p0[0] += bf2f(v.x); p1[0] += bf2f(v.y);
    }
    float u0 = ((p0[0] + p0[1]) + (p0[2] + p0[3])) + ((p0[4] + p0[5]) + (p0[6] + p0[7]));
    float u1 = ((p1[0] + p1[1]) + (p1[2] + p1[3])) + ((p1[4] + p1[5]) + (p1[6] + p1[7]));
    if (t == 0) u0 = 0.f;
    float s1 = wredsum(u0 * u0 + u1 * u1);
    float n = sqrtf(fmaxf(s1 + EPSF, 1e-6f));
    float fac = fsinh(fminf(n, 50.f)) / n;
    float S2 = fac * fac * s1;
    float first = sqrtf(1.f + S2);
    float dist = arcosh_f(first + EPSF);
    float C = dist / sqrtf(S2 + EPSF) * fac;
    ushort2 o;
    o.x = f2bf(C * u0);
    o.y = f2bf(C * u1);
    *reinterpret_cast<ushort2*>(Ab + (size_t)i * 256 + 2 * t) = o;
}

// ---------- W conversion (all 3 layers, one launch) ----------
__global__ void k_convw3(const float* __restrict__ W0, const float* __restrict__ W1,
                         const float* __restrict__ W2,
                         ushort_t* __restrict__ Wb0, ushort_t* __restrict__ Wb1,
                         ushort_t* __restrict__ Wb2,
                         int o1, int i1, int Kp1, int o2, int i2, int Kp2,
                         int o3, int i3, int Kp3, int t1, int t2, int t3) {
    int idx = blockIdx.x * blockDim.x + threadIdx.x;
    const float* W; ushort_t* Wb; int ncols, K, Kp, shift;
    if (idx < t1) { W = W0; Wb = Wb0; ncols = o1; K = i1; Kp = Kp1; shift = 1; }
    else if (idx < t1 + t2) { idx -= t1; W = W1; Wb = Wb1; ncols = o2; K = i2; Kp = Kp2; shift = 0; }
    else if (idx < t1 + t2 + t3) { idx -= t1 + t2; W = W2; Wb = Wb2; ncols = o3; K = i3; Kp = Kp3; shift = 0; }
    else return;
    int o = idx / Kp, kk = idx - o * Kp;
    int ks = kk - shift;
    float v = 0.f;
    if (o < ncols && ks >= 0 && ks < K) v = W[(size_t)o * K + ks];
    Wb[idx] = f2bf(v);
}

// ---------- fused layer-1 GEMM + full epilogue: out = C_row * relu(A@W^T + b), in-place ----------
__global__ __launch_bounds__(256) void k_gemmf(const ushort_t* __restrict__ Ab, int lda,
                                               const ushort_t* __restrict__ Wb, int ldw,
                                               const float* __restrict__ bias,
                                               ushort_t* __restrict__ Out,
                                               int Kp, int ncols) {
    __shared__ ushort_t As[128 * 32];
    __shared__ ushort_t Bs[128 * 32];
    __shared__ float s1buf[2][128];
    __shared__ float spbuf[2][128];
    __shared__ float Cbuf[128];
    int tid = threadIdx.x;
    int lane = tid & 63, wv = tid >> 6;
    int bm = blockIdx.x * 128;
    int r = lane & 15, g4 = lane >> 4;
    int wr = (wv >> 1) * 64, wc = (wv & 1) * 64;
    int half = wv & 1;

    f32x4 acc[4][4] = {};
    for (int k0 = 0; k0 < Kp; k0 += 32) {
#pragma unroll
        for (int ci = 0; ci < 2; ++ci) {
            int L = (wv * 2 + ci) * 1024 + lane * 16;
            int row = L >> 6, kb = L & 63;
            const char* ga = (const char*)Ab + ((size_t)(bm + row) * lda + k0) * 2 + kb;
            llds16(ga, (char*)As + (wv * 2 + ci) * 1024);
            const char* gb = (const char*)Wb + ((size_t)(row) * ldw + k0) * 2 + kb;
            llds16(gb, (char*)Bs + (wv * 2 + ci) * 1024);
        }
        __syncthreads();
        bf16x8 af[4], bfr[4];
#pragma unroll
        for (int m = 0; m < 4; ++m)
            af[m] = *reinterpret_cast<const bf16x8*>((const char*)As + (wr + m * 16 + r) * 64 + g4 * 16);
#pragma unroll
        for (int n2 = 0; n2 < 4; ++n2)
            bfr[n2] = *reinterpret_cast<const bf16x8*>((const char*)Bs + (wc + n2 * 16 + r) * 64 + g4 * 16);
#pragma unroll
        for (int m = 0; m < 4; ++m)
#pragma unroll
            for (int n2 = 0; n2 < 4; ++n2)
                acc[m][n2] = __builtin_amdgcn_mfma_f32_16x16x32_bf16(af[m], bfr[n2], acc[m][n2], 0, 0, 0);
        __syncthreads();
    }
    float bv[4];
#pragma unroll
    for (int n2 = 0; n2 < 4; ++n2) {
        int col = wc + n2 * 16 + r;
        bv[n2] = (col < ncols) ? bias[col] : 0.f;
    }
#pragma unroll
    for (int m = 0; m < 4; ++m) {
#pragma unroll
        for (int j = 0; j < 4; ++j) {
            float s1l = 0.f, spl = 0.f;
#pragma unroll
            for (int n2 = 0; n2 < 4; ++n2) {
                int col = wc + n2 * 16 + r;
                float y = (col < ncols) ? (acc[m][n2][j] + bv[n2]) : 0.f;
                acc[m][n2][j] = y;
                s1l += y * y;
                float ym = fmaxf(y, 0.f);
                spl += ym * ym;
            }
#pragma unroll
            for (int off = 1; off < 16; off <<= 1) {
                s1l += __shfl_xor(s1l, off, 64);
                spl += __shfl_xor(spl, off, 64);
            }
            if (r == 0) {
                int row = wr + m * 16 + g4 * 4 + j;
                s1buf[half][row] = s1l;
                spbuf[half][row] = spl;
            }
        }
    }
    __syncthreads();
    if (tid < 128) {
        Cbuf[tid] = ep_coef(s1buf[0][tid] + s1buf[1][tid], spbuf[0][tid] + spbuf[1][tid]);
    }
    __syncthreads();
#pragma unroll
    for (int m = 0; m < 4; ++m) {
#pragma unroll
        for (int j = 0; j < 4; ++j) {
            int rloc = wr + m * 16 + g4 * 4 + j;
            float C = Cbuf[rloc];
            size_t rowoff = (size_t)(bm + rloc) * 256;
#pragma unroll
            for (int n2 = 0; n2 < 4; ++n2) {
                int col = wc + n2 * 16 + r;
                Out[rowoff + col] = f2bf(C * fmaxf(acc[m][n2][j], 0.f));
            }
        }
    }
}

// ---------- layer-2 GEMM: writes relu(Y2) bf16 (pad-zeroed) + per-row partial s1/sp ----------
__global__ __launch_bounds__(256) void k_gemm2(const ushort_t* __restrict__ Ab, int lda,
                                               const ushort_t* __restrict__ Wb, int ldw,
                                               const float* __restrict__ bias,
                                               ushort_t* __restrict__ Yb, int ldy,
                                               float* __restrict__ pS1, float* __restrict__ pSp,
                                               int NBY, int Kp, int ncols) {
    __shared__ ushort_t As[128 * 32];
    __shared__ ushort_t Bs[128 * 32];
    __shared__ float s1buf[2][128];
    __shared__ float spbuf[2][128];
    int tid = threadIdx.x;
    int lane = tid & 63, wv = tid >> 6;
    int bm = blockIdx.x * 128, bn = blockIdx.y * 128, by = blockIdx.y;
    int r = lane & 15, g4 = lane >> 4;
    int wr = (wv >> 1) * 64, wc = (wv & 1) * 64;
    int half = wv & 1;

    f32x4 acc[4][4] = {};
    for (int k0 = 0; k0 < Kp; k0 += 32) {
#pragma unroll
        for (int ci = 0; ci < 2; ++ci) {
            int L = (wv * 2 + ci) * 1024 + lane * 16;
            int row = L >> 6, kb = L & 63;
            const char* ga = (const char*)Ab + ((size_t)(bm + row) * lda + k0) * 2 + kb;
            llds16(ga, (char*)As + (wv * 2 + ci) * 1024);
            const char* gb = (const char*)Wb + ((size_t)(bn + row) * ldw + k0) * 2 + kb;
            llds16(gb, (char*)Bs + (wv * 2 + ci) * 1024);
        }
        __syncthreads();
        bf16x8 af[4], bfr[4];
#pragma unroll
        for (int m = 0; m < 4; ++m)
            af[m] = *reinterpret_cast<const bf16x8*>((const char*)As + (wr + m * 16 + r) * 64 + g4 * 16);
#pragma unroll
        for (int n2 = 0; n2 < 4; ++n2)
            bfr[n2] = *reinterpret_cast<const bf16x8*>((const char*)Bs + (wc + n2 * 16 + r) * 64 + g4 * 16);
#pragma unroll
        for (int m = 0; m < 4; ++m)
#pragma unroll
            for (int n2 = 0; n2 < 4; ++n2)
                acc[m][n2] = __builtin_amdgcn_mfma_f32_16x16x32_bf16(af[m], bfr[n2], acc[m][n2], 0, 0, 0);
        __syncthreads();
    }
    float bv[4];
#pragma unroll
    for (int n2 = 0; n2 < 4; ++n2) {
        int col = bn + wc + n2 * 16 + r;
        bv[n2] = (col < ncols) ? bias[col] : 0.f;
    }
#pragma unroll
    for (int m = 0; m < 4; ++m) {
#pragma unroll
        for (int j = 0; j < 4; ++j) {
            int rloc = wr + m * 16 + g4 * 4 + j;
            size_t rowoff = (size_t)(bm + rloc) * ldy;
            float s1l = 0.f, spl = 0.f;
#pragma unroll
            for (int n2 = 0; n2 < 4; ++n2) {
                int col = bn + wc + n2 * 16 + r;
                float y = (col < ncols) ? (acc[m][n2][j] + bv[n2]) : 0.f;
                float ym = fmaxf(y, 0.f);
                s1l += y * y;
                spl += ym * ym;
                Yb[rowoff + col] = f2bf(ym);
            }
#pragma unroll
            for (int off = 1; off < 16; off <<= 1) {
                s1l += __shfl_xor(s1l, off, 64);
                spl += __shfl_xor(spl, off, 64);
            }
            if (r == 0) {
                s1buf[half][rloc] = s1l;
                spbuf[half][rloc] = spl;
            }
        }
    }
    __syncthreads();
    if (tid < 128) {
        int row = bm + tid;
        pS1[(size_t)row * NBY + by] = s1buf[0][tid] + s1buf[1][tid];
        pSp[(size_t)row * NBY + by] = spbuf[0][tid] + spbuf[1][tid];
    }
}

// ---------- layer-3 GEMM: y = C2[row]*acc + bias; writes Y3 bf16 + partial s1/sp ----------
__global__ __launch_bounds__(256) void k_gemm3(const ushort_t* __restrict__ Ab, int lda,
                                               const ushort_t* __restrict__ Wb, int ldw,
                                               const float* __restrict__ bias,
                                               const float* __restrict__ coef2,
                                               ushort_t* __restrict__ Yb, int ldy,
                                               float* __restrict__ pS1, float* __restrict__ pSp,
                                               int NBY, int Kp, int ncols) {
    __shared__ ushort_t As[128 * 32];
    __shared__ ushort_t Bs[128 * 32];
    __shared__ float s1buf[2][128];
    __shared__ float spbuf[2][128];
    int tid = threadIdx.x;
    int lane = tid & 63, wv = tid >> 6;
    int bm = blockIdx.x * 128, bn = blockIdx.y * 128, by = blockIdx.y;
    int r = lane & 15, g4 = lane >> 4;
    int wr = (wv >> 1) * 64, wc = (wv & 1) * 64;
    int half = wv & 1;

    f32x4 acc[4][4] = {};
    for (int k0 = 0; k0 < Kp; k0 += 32) {
#pragma unroll
        for (int ci = 0; ci < 2; ++ci) {
            int L = (wv * 2 + ci) * 1024 + lane * 16;
            int row = L >> 6, kb = L & 63;
            const char* ga = (const char*)Ab + ((size_t)(bm + row) * lda + k0) * 2 + kb;
            llds16(ga, (char*)As + (wv * 2 + ci) * 1024);
            const char* gb = (const char*)Wb + ((size_t)(bn + row) * ldw + k0) * 2 + kb;
            llds16(gb, (char*)Bs + (wv * 2 + ci) * 1024);
        }
        __syncthreads();
        bf16x8 af[4], bfr[4];
#pragma unroll
        for (int m = 0; m < 4; ++m)
            af[m] = *reinterpret_cast<const bf16x8*>((const char*)As + (wr + m * 16 + r) * 64 + g4 * 16);
#pragma unroll
        for (int n2 = 0; n2 < 4; ++n2)
            bfr[n2] = *reinterpret_cast<const bf16x8*>((const char*)Bs + (wc + n2 * 16 + r) * 64 + g4 * 16);
#pragma unroll
        for (int m = 0; m < 4; ++m)
#pragma unroll
            for (int n2 = 0; n2 < 4; ++n2)
                acc[m][n2] = __builtin_amdgcn_mfma_f32_16x16x32_bf16(af[m], bfr[n2], acc[m][n2], 0, 0, 0);
        __syncthreads();
    }
    float bv[4];
#pragma unroll
    for (int n2 = 0; n2 < 4; ++n2) {
        int col = bn + wc + n2 * 16 + r;
        bv[n2] = (col < ncols) ? bias[col] : 0.f;
    }
#pragma unroll
    for (int m = 0; m < 4; ++m) {
#pragma unroll
        for (int j = 0; j < 4; ++j) {
            int rloc = wr + m * 16 + g4 * 4 + j;
            float c2 = coef2[bm + rloc];
            size_t rowoff = (size_t)(bm + rloc) * ldy;
            float s1l = 0.f, spl = 0.f;
#pragma unroll
            for (int n2 = 0; n2 < 4; ++n2) {
                int col = bn + wc + n2 * 16 + r;
                float y = (col < ncols) ? (c2 * acc[m][n2][j] + bv[n2]) : 0.f;
                float ym = fmaxf(y, 0.f);
                s1l += y * y;
                spl += ym * ym;
                Yb[rowoff + col] = f2bf(y);
            }
#pragma unroll
            for (int off = 1; off < 16; off <<= 1) {
                s1l += __shfl_xor(s1l, off, 64);
                spl += __shfl_xor(spl, off, 64);
            }
            if (r == 0) {
                s1buf[half][rloc] = s1l;
                spbuf[half][rloc] = spl;
            }
        }
    }
    __syncthreads();
    if (tid < 128) {
        int row = bm + tid;
        pS1[(size_t)row * NBY + by] = s1buf[0][tid] + s1buf[1][tid];
        pSp[(size_t)row * NBY + by] = spbuf[0][tid] + spbuf[1][tid];
    }
}

// ---------- tiny coef kernel: combine P partials per row -> ep_coef ----------
template <int P>
__global__ __launch_bounds__(256) void k_cf(const float* __restrict__ pS1,
                                            const float* __restrict__ pSp,
                                            float* __restrict__ coef, int M) {
    int i = blockIdx.x * 256 + threadIdx.x;
    if (i >= M) return;
    float s1 = 0.f, sp = 0.f;
#pragma unroll
    for (int p = 0; p < P; ++p) { s1 += pS1[(size_t)i * P + p]; sp += pSp[(size_t)i * P + p]; }
    coef[i] = ep_coef(s1, sp);
}

// ---------- mean partials: reads Y + coef, accumulates C*relu(y). deterministic ----------
__global__ __launch_bounds__(192) void k_mean(const ushort_t* __restrict__ Y,
                                              const float* __restrict__ coef,
                                              float* __restrict__ partials, int N, int chunk) {
    int b = blockIdx.x;
    int t = threadIdx.x;
    int lo = b * chunk;
    int hi = lo + chunk; if (hi > N) hi = N;
    bool lastpair = (t == 191);
    float a0 = 0.f, a1 = 0.f;
    const ushort_t* p = Y + (size_t)lo * 384 + 2 * t;
    for (int n = lo; n < hi; ++n, p += 384) {
        float c = coef[n];
        ushort2 v = *reinterpret_cast<const ushort2*>(p);
        a0 += c * fmaxf(bf2f(v.x), 0.f);
        if (!lastpair) a1 += c * fmaxf(bf2f(v.y), 0.f);
    }
    float* orow = partials + (size_t)b * 384;
    orow[2 * t] = a0;
    orow[2 * t + 1] = a1;
}

// ---------- stage-2 mean reduce ----------
__global__ __launch_bounds__(256) void k_mred(const float* __restrict__ partials,
                                              float* __restrict__ hm, int nparts, int N) {
    __shared__ float sb[256];
    int j = blockIdx.x, t = threadIdx.x;
    float v = 0.f;
    for (int p = t; p < nparts; p += 256) v += partials[(size_t)p * 384 + j];
    sb[t] = v; __syncthreads();
    for (int st = 128; st > 0; st >>= 1) { if (t < st) sb[t] += sb[t + st]; __syncthreads(); }
    if (t == 0) hm[j] = sb[0] / (float)N;
}

// ---------- classifier head (libm precision retained; negligible cost) ----------
__global__ __launch_bounds__(64) void k_head(const float* __restrict__ hm,
                                             const float* __restrict__ Wc,
                                             const float* __restrict__ bc,
                                             float* __restrict__ dout, int ic, int oc) {
    int t = threadIdx.x;
    float h[6];
    float ss = 0.f;
#pragma unroll
    for (int c = 0; c < 6; ++c) {
        int j = t + 64 * c;
        h[c] = (j < ic) ? hm[j] : 0.f;
        ss += h[c] * h[c];
    }
    float ssum = wredsum(ss);
    float dist = logf(1.0f + EPSF + sqrtf((1.0f + EPSF) * (1.0f + EPSF) - 1.0f));
    float scl = dist / sqrtf(ssum + EPSF);
    float mxv[9];
#pragma unroll
    for (int o = 0; o < 9; ++o) {
        float p = 0.f;
        if (o < oc) {
#pragma unroll
            for (int c = 0; c < 6; ++c) {
                int j = t + 64 * c;
                if (j < ic) p += h[c] * Wc[(size_t)o * ic + j];
            }
        }
        float s = wredsum(p);
        mxv[o] = (o < oc) ? (scl * s + bc[o]) : 0.f;
    }
    if (t == 0) {
        float y[10], tt[10], lt[11], p[11], t3[11];
        float s1 = 0.f, sab = 0.f;
        for (int j = 0; j < 9; ++j) {
            y[j] = (j < oc) ? mxv[j] : 0.f;
            s1 += y[j] * y[j]; sab += fabsf(y[j]);
        }
        bool allz = (sab == 0.f);
        float n = sqrtf(fmaxf(s1 + EPSF, 1e-6f));
        float sh = sinhf(fminf(n, 50.f));
        float s2 = 0.f;
        for (int j = 0; j < oc; ++j) { tt[j] = allz ? 0.f : sh * y[j] / n; s2 += tt[j] * tt[j]; }
        float first = allz ? 0.f : sqrtf(1.f + s2);
        dout[0] = first;
        for (int j = 0; j < oc; ++j) dout[1 + j] = tt[j];
        float xx = fmaxf(first + EPSF, 1.0f + EPSF);
        float dist2 = logf(xx + sqrtf(xx * xx - 1.0f));
        float nrm2 = sqrtf(s2 + EPSF);
        lt[0] = 0.f;
        for (int j = 0; j < oc; ++j) lt[1 + j] = dist2 / nrm2 * tt[j];
        float m = lt[0];
        for (int j = 1; j <= oc; ++j) m = fmaxf(m, lt[j]);
        float es = 0.f;
        for (int j = 0; j <= oc; ++j) { p[j] = expf(lt[j] - m); es += p[j]; }
        for (int j = 0; j <= oc; ++j) p[j] /= es;
        p[0] = 0.f;
        float s3 = 0.f;
        for (int j = 1; j <= oc; ++j) s3 += p[j] * p[j];
        float n3 = sqrtf(fmaxf(s3 + EPSF, 1e-6f));
        float sh3 = sinhf(fminf(n3, 50.f));
        float s4 = 0.f;
        for (int j = 1; j <= oc; ++j) { t3[j] = sh3 * p[j] / n3; s4 += t3[j] * t3[j]; }
        dout[1 + oc] = sqrtf(1.f + s4);
        for (int j = 1; j <= oc; ++j) dout[1 + oc + j] = t3[j];
    }
}

extern "C" void kernel_launch(void* const* d_in, const int* in_sizes, int n_in,
                              void* d_out, int out_size, void* d_ws, size_t ws_size,
                              hipStream_t stream) {
    if (n_in < 10) return;
    const float* x   = (const float*)d_in[0];
    const int*   ei  = (const int*)d_in[1];
    const float* W0  = (const float*)d_in[2];
    const float* b0  = (const float*)d_in[3];
    const float* W1  = (const float*)d_in[4];
    const float* b1  = (const float*)d_in[5];
    const float* W2  = (const float*)d_in[6];
    const float* b2  = (const float*)d_in[7];
    const float* Wc  = (const float*)d_in[8];
    const float* bc  = (const float*)d_in[9];
    float* dout = (float*)d_out;

    int N = in_sizes[0] / 128;
    int E = in_sizes[1] / 2;
    int o1 = in_sizes[3];
    int i1 = in_sizes[2] / o1;
    int o2 = in_sizes[5];
    int i2 = in_sizes[4] / o2;
    int o3 = in_sizes[7];
    int i3 = in_sizes[6] / o3;
    int oc = in_sizes[9];
    int ic = in_sizes[8] / oc;

    int M_pad = ((N + 127) / 128) * 128;
    int Kp1 = ((i1 + 31) / 32) * 32;
    int Kp2 = ((i2 + 31) / 32) * 32;
    int Kp3 = ((i3 + 31) / 32) * 32;
    int Np2 = ((o2 + 127) / 128) * 128;
    int Np3 = ((o3 + 127) / 128) * 128;
    int Np1 = 128;

    const int* esrc = ei;
    const int* edst = ei + E;

    char* ws = (char*)d_ws;
    auto alloc = [&](size_t bytes) {
        char* p = ws;
        ws += (bytes + 511) & ~(size_t)511;
        return p;
    };
    ushort_t* Ab     = (ushort_t*)alloc((size_t)M_pad * 256 * 2);   // A (lo) + xt0 (hi)
    ushort_t* R      = (ushort_t*)alloc((size_t)M_pad * 256 * 2);   // relu(Y2)
    ushort_t* Y3     = (ushort_t*)alloc((size_t)M_pad * 384 * 2);   // layer-3 output
    ushort_t* Wb0    = (ushort_t*)alloc((size_t)Np1 * Kp1 * 2);
    ushort_t* Wb1    = (ushort_t*)alloc((size_t)Np2 * Kp2 * 2);
    ushort_t* Wb2    = (ushort_t*)alloc((size_t)Np3 * Kp3 * 2);
    int*      ebuf   = (int*)alloc((size_t)E * 4);
    int*      gcnt   = (int*)alloc((size_t)256 * 64 * 4);
    int*      bstart = (int*)alloc(128 * 4);
    int*      row_ptr= (int*)alloc((size_t)(N + 1) * 4);
    int*      srcl   = (int*)alloc((size_t)E * 4);
    float*    pS1_2  = (float*)alloc((size_t)M_pad * 2 * 4);
    float*    pSp_2  = (float*)alloc((size_t)M_pad * 2 * 4);
    float*    pS1_3  = (float*)alloc((size_t)M_pad * 3 * 4);
    float*    pSp_3  = (float*)alloc((size_t)M_pad * 3 * 4);
    float*    coef2  = (float*)alloc((size_t)M_pad * 4);
    float*    coef3  = (float*)alloc((size_t)M_pad * 4);
    float*    partials = (float*)alloc((size_t)2048 * 384 * 4);
    float*    hmbuf  = (float*)alloc(512 * 4);
    (void)ws_size;

    int NBKT = (N + 1023) >> 10;
    int EPB = 4096;
    int NBLK_E = (E + EPB - 1) / EPB;

    int t1 = Np1 * Kp1, t2 = Np2 * Kp2, t3 = Np3 * Kp3;
    k_convw3<<<dim3((t1 + t2 + t3 + 255) / 256), dim3(256), 0, stream>>>(
        W0, W1, W2, Wb0, Wb1, Wb2, o1, i1, Kp1, o2, i2, Kp2, o3, i3, Kp3, t1, t2, t3);
    // 1. log_map_zero(x) -> xt0 bf16
    k_log0<<<dim3(N), dim3(64), 0, stream>>>(x, (char*)Ab, N);
    // 2. bucket partition + per-bucket exact CSR
    k_c1<<<dim3(NBLK_E), dim3(256), 0, stream>>>(edst, gcnt, E, NBKT, EPB);
    k_c2<<<dim3(1), dim3(64), 0, stream>>>(gcnt, bstart, NBLK_E, NBKT);
    k_c3<<<dim3(NBLK_E), dim3(256), 0, stream>>>(esrc, edst, gcnt, ebuf, E, NBKT, EPB);
    k_c4<<<dim3(NBKT), dim3(1024), 0, stream>>>(ebuf, bstart, row_ptr, srcl, N, NBKT, E);
    // 3. aggregate + collapsed epilogue -> A (bf16)
    k_agg<<<dim3(N), dim3(64), 0, stream>>>((const char*)Ab, row_ptr, srcl, Ab, N);
    // 4. layer 1: fused GEMM + full epilogue, in-place on Ab
    k_gemmf<<<dim3(M_pad / 128), dim3(256), 0, stream>>>(Ab, 256, Wb0, Kp1, b0, Ab, Kp1, o1);
    // 5. layer 2: GEMM -> relu(Y2) + per-row partials; tiny coef kernel
    k_gemm2<<<dim3(M_pad / 128, Np2 / 128), dim3(256), 0, stream>>>(
        Ab, 256, Wb1, Kp2, b1, R, 256, pS1_2, pSp_2, Np2 / 128, Kp2, o2);
    k_cf<2><<<dim3((M_pad + 255) / 256), dim3(256), 0, stream>>>(pS1_2, pSp_2, coef2, M_pad);
    // 6. layer 3: GEMM with C2 row-scale folded in -> Y3 + partials; tiny coef kernel
    k_gemm3<<<dim3(M_pad / 128, Np3 / 128), dim3(256), 0, stream>>>(
        R, 256, Wb2, Kp3, b2, coef2, Y3, 384, pS1_3, pSp_3, Np3 / 128, Kp3, o3);
    k_cf<3><<<dim3((M_pad + 255) / 256), dim3(256), 0, stream>>>(pS1_3, pSp_3, coef3, M_pad);
    // 7. deterministic mean of ht = C3 * relu(Y3)
    int NBLK = 2048;
    int chunk = (N + NBLK - 1) / NBLK;
    k_mean<<<dim3(NBLK), dim3(192), 0, stream>>>(Y3, coef3, partials, N, chunk);
    k_mred<<<dim3(383), dim3(256), 0, stream>>>(partials, hmbuf, NBLK, N);
    // 8. classifier head
    k_head<<<dim3(1), dim3(64), 0, stream>>>(hmbuf, Wc, bc, dout, ic, oc);
}